// Round 8
// baseline (219.217 us; speedup 1.0000x reference)
//
#include <hip/hip_runtime.h>
#include <stdint.h>

#define DIM     2048
#define NEXP    64
#define NCHUNK  32        // K chunks of 64
#define TAU     2e-4f     // near-tie threshold on relative prob gaps

#define WFRAG_USHORTS (NCHUNK * 8192)        // 512 KB fragment image
#define FLAGS_OFF     (WFRAG_USHORTS * 2)    // byte offset of flags in d_ws

typedef __attribute__((ext_vector_type(8))) short bf16x8;
typedef __attribute__((ext_vector_type(8))) unsigned short u16x8;
typedef __attribute__((ext_vector_type(4))) float f32x4;

__device__ inline unsigned short bf16_rne(float f) {
    uint32_t u = __float_as_uint(f);
    return (unsigned short)((u + 0x7FFFu + ((u >> 16) & 1u)) >> 16);
}
__device__ inline float bf16_to_f(unsigned short h) {
    return __uint_as_float(((uint32_t)h) << 16);
}
__device__ inline uint64_t mono64(double d) {
    uint64_t u = (uint64_t)__double_as_longlong(d);
    return (u >> 63) ? ~u : (u | 0x8000000000000000ull);
}
__device__ inline double unmono64(uint64_t m) {
    uint64_t b = (m >> 63) ? (m & 0x7fffffffffffffffull) : ~m;
    return __longlong_as_double((long long)b);
}

#define SPL(F, HV, LV, J)  { unsigned short _h = bf16_rne(F); HV[J] = _h; LV[J] = bf16_rne((F) - bf16_to_f(_h)); }
#define SPLS(F, HV, LV, J) { unsigned short _h = bf16_rne(F); HV[J] = (short)_h; LV[J] = (short)bf16_rne((F) - bf16_to_f(_h)); }

// ---- Kernel 0: split w into bf16 hi/lo B-fragment image ----
// layout (ushort): [c:32][ks:2][t:4][plane:2][lane:64][j:8]
__global__ __launch_bounds__(256) void wsplit_kernel(
    const float* __restrict__ wgt, unsigned short* __restrict__ wf)
{
    int g = blockIdx.x * 256 + threadIdx.x;   // 0..16383 = c*512 + s*256 + t*64 + l
    int l = g & 63;
    int t = (g >> 6) & 3;
    int s = (g >> 8) & 1;
    int c = g >> 9;
    int e = (l & 15) + 16 * t;
    int k = c * 64 + s * 32 + ((l >> 4) * 8);
    const float* wp = wgt + (size_t)e * DIM + k;
    float4 f0 = *(const float4*)(wp);
    float4 f1 = *(const float4*)(wp + 4);
    u16x8 h, lo;
    SPL(f0.x, h, lo, 0) SPL(f0.y, h, lo, 1) SPL(f0.z, h, lo, 2) SPL(f0.w, h, lo, 3)
    SPL(f1.x, h, lo, 4) SPL(f1.y, h, lo, 5) SPL(f1.z, h, lo, 6) SPL(f1.w, h, lo, 7)
    size_t base = ((((size_t)(c * 2 + s) * 4 + t) * 2 + 0) * 64 + l) * 8;
    *(u16x8*)(wf + base)       = h;
    *(u16x8*)(wf + base + 512) = lo;   // plane stride = 64*8
}

// ---- Pass 1: bf16x3 MFMA GEMM (no LDS, no barriers) + softmax + top-8 + flag ----
__global__ __launch_bounds__(64) void moe_gate_mfma_kernel(
    const float* __restrict__ x, const unsigned short* __restrict__ wf,
    float* __restrict__ out, int ntok, unsigned char* __restrict__ flags)
{
    __shared__ __align__(16) float ls[16][68];

    const int lane = threadIdx.x;
    const int t0   = blockIdx.x * 16;
    const int l15  = lane & 15;
    const int lg   = lane >> 4;

    const float* xp = x + (size_t)(t0 + l15) * DIM + lg * 8;
    const unsigned short* wl = wf + lane * 8;

    f32x4 acc0 = {0.f,0.f,0.f,0.f}, acc1 = {0.f,0.f,0.f,0.f};
    f32x4 acc2 = {0.f,0.f,0.f,0.f}, acc3 = {0.f,0.f,0.f,0.f};

    float4 pa0 = *(const float4*)(xp);
    float4 pa1 = *(const float4*)(xp + 4);
    float4 pa2 = *(const float4*)(xp + 32);
    float4 pa3 = *(const float4*)(xp + 36);

    for (int c = 0; c < NCHUNK; ++c) {
        float4 pb0 = pa0, pb1 = pa1, pb2 = pa2, pb3 = pa3;
        if (c + 1 < NCHUNK) {
            const float* xn = xp + (c + 1) * 64;
            pb0 = *(const float4*)(xn);
            pb1 = *(const float4*)(xn + 4);
            pb2 = *(const float4*)(xn + 32);
            pb3 = *(const float4*)(xn + 36);
        }
        bf16x8 Ah0, Al0, Ah1, Al1;
        SPLS(pa0.x, Ah0, Al0, 0) SPLS(pa0.y, Ah0, Al0, 1) SPLS(pa0.z, Ah0, Al0, 2) SPLS(pa0.w, Ah0, Al0, 3)
        SPLS(pa1.x, Ah0, Al0, 4) SPLS(pa1.y, Ah0, Al0, 5) SPLS(pa1.z, Ah0, Al0, 6) SPLS(pa1.w, Ah0, Al0, 7)
        SPLS(pa2.x, Ah1, Al1, 0) SPLS(pa2.y, Ah1, Al1, 1) SPLS(pa2.z, Ah1, Al1, 2) SPLS(pa2.w, Ah1, Al1, 3)
        SPLS(pa3.x, Ah1, Al1, 4) SPLS(pa3.y, Ah1, Al1, 5) SPLS(pa3.z, Ah1, Al1, 6) SPLS(pa3.w, Ah1, Al1, 7)

        const unsigned short* wc = wl + (size_t)c * 8192;
        // ks = 0
        {
            bf16x8 Bh, Bl;
            Bh = *(const bf16x8*)(wc + 0);    Bl = *(const bf16x8*)(wc + 512);
            acc0 = __builtin_amdgcn_mfma_f32_16x16x32_bf16(Ah0, Bh, acc0, 0, 0, 0);
            acc0 = __builtin_amdgcn_mfma_f32_16x16x32_bf16(Ah0, Bl, acc0, 0, 0, 0);
            acc0 = __builtin_amdgcn_mfma_f32_16x16x32_bf16(Al0, Bh, acc0, 0, 0, 0);
            Bh = *(const bf16x8*)(wc + 1024); Bl = *(const bf16x8*)(wc + 1536);
            acc1 = __builtin_amdgcn_mfma_f32_16x16x32_bf16(Ah0, Bh, acc1, 0, 0, 0);
            acc1 = __builtin_amdgcn_mfma_f32_16x16x32_bf16(Ah0, Bl, acc1, 0, 0, 0);
            acc1 = __builtin_amdgcn_mfma_f32_16x16x32_bf16(Al0, Bh, acc1, 0, 0, 0);
            Bh = *(const bf16x8*)(wc + 2048); Bl = *(const bf16x8*)(wc + 2560);
            acc2 = __builtin_amdgcn_mfma_f32_16x16x32_bf16(Ah0, Bh, acc2, 0, 0, 0);
            acc2 = __builtin_amdgcn_mfma_f32_16x16x32_bf16(Ah0, Bl, acc2, 0, 0, 0);
            acc2 = __builtin_amdgcn_mfma_f32_16x16x32_bf16(Al0, Bh, acc2, 0, 0, 0);
            Bh = *(const bf16x8*)(wc + 3072); Bl = *(const bf16x8*)(wc + 3584);
            acc3 = __builtin_amdgcn_mfma_f32_16x16x32_bf16(Ah0, Bh, acc3, 0, 0, 0);
            acc3 = __builtin_amdgcn_mfma_f32_16x16x32_bf16(Ah0, Bl, acc3, 0, 0, 0);
            acc3 = __builtin_amdgcn_mfma_f32_16x16x32_bf16(Al0, Bh, acc3, 0, 0, 0);
        }
        // ks = 1 (offset +4096)
        {
            bf16x8 Bh, Bl;
            Bh = *(const bf16x8*)(wc + 4096); Bl = *(const bf16x8*)(wc + 4608);
            acc0 = __builtin_amdgcn_mfma_f32_16x16x32_bf16(Ah1, Bh, acc0, 0, 0, 0);
            acc0 = __builtin_amdgcn_mfma_f32_16x16x32_bf16(Ah1, Bl, acc0, 0, 0, 0);
            acc0 = __builtin_amdgcn_mfma_f32_16x16x32_bf16(Al1, Bh, acc0, 0, 0, 0);
            Bh = *(const bf16x8*)(wc + 5120); Bl = *(const bf16x8*)(wc + 5632);
            acc1 = __builtin_amdgcn_mfma_f32_16x16x32_bf16(Ah1, Bh, acc1, 0, 0, 0);
            acc1 = __builtin_amdgcn_mfma_f32_16x16x32_bf16(Ah1, Bl, acc1, 0, 0, 0);
            acc1 = __builtin_amdgcn_mfma_f32_16x16x32_bf16(Al1, Bh, acc1, 0, 0, 0);
            Bh = *(const bf16x8*)(wc + 6144); Bl = *(const bf16x8*)(wc + 6656);
            acc2 = __builtin_amdgcn_mfma_f32_16x16x32_bf16(Ah1, Bh, acc2, 0, 0, 0);
            acc2 = __builtin_amdgcn_mfma_f32_16x16x32_bf16(Ah1, Bl, acc2, 0, 0, 0);
            acc2 = __builtin_amdgcn_mfma_f32_16x16x32_bf16(Al1, Bh, acc2, 0, 0, 0);
            Bh = *(const bf16x8*)(wc + 7168); Bl = *(const bf16x8*)(wc + 7680);
            acc3 = __builtin_amdgcn_mfma_f32_16x16x32_bf16(Ah1, Bh, acc3, 0, 0, 0);
            acc3 = __builtin_amdgcn_mfma_f32_16x16x32_bf16(Ah1, Bl, acc3, 0, 0, 0);
            acc3 = __builtin_amdgcn_mfma_f32_16x16x32_bf16(Al1, Bh, acc3, 0, 0, 0);
        }
        pa0 = pb0; pa1 = pb1; pa2 = pb2; pa3 = pb3;
    }

    // ---- transpose logits via LDS: ls[token][expert] (C/D: row=lg*4+i, col=t*16+l15) ----
    __syncthreads();
    {
        const int rb = lg * 4;
        ls[rb + 0][ 0 + l15] = acc0[0]; ls[rb + 1][ 0 + l15] = acc0[1];
        ls[rb + 2][ 0 + l15] = acc0[2]; ls[rb + 3][ 0 + l15] = acc0[3];
        ls[rb + 0][16 + l15] = acc1[0]; ls[rb + 1][16 + l15] = acc1[1];
        ls[rb + 2][16 + l15] = acc1[2]; ls[rb + 3][16 + l15] = acc1[3];
        ls[rb + 0][32 + l15] = acc2[0]; ls[rb + 1][32 + l15] = acc2[1];
        ls[rb + 2][32 + l15] = acc2[2]; ls[rb + 3][32 + l15] = acc2[3];
        ls[rb + 0][48 + l15] = acc3[0]; ls[rb + 1][48 + l15] = acc3[1];
        ls[rb + 2][48 + l15] = acc3[2]; ls[rb + 3][48 + l15] = acc3[3];
    }
    __syncthreads();

    // ---- softmax + top-8: 4 lanes per token, 16 experts each (R6/R7 construct) ----
    const int tok = l15;
    const int sub = lg;

    float r[16];
#pragma unroll
    for (int k = 0; k < 4; ++k) {
        float4 v = *(const float4*)(&ls[tok][sub * 16 + 4 * k]);
        r[4 * k] = v.x; r[4 * k + 1] = v.y; r[4 * k + 2] = v.z; r[4 * k + 3] = v.w;
    }

    float m = r[0];
#pragma unroll
    for (int i = 1; i < 16; ++i) m = fmaxf(m, r[i]);
    m = fmaxf(m, __shfl_xor(m, 16));
    m = fmaxf(m, __shfl_xor(m, 32));

    float ex[16]; float s = 0.f;
#pragma unroll
    for (int i = 0; i < 16; ++i) { ex[i] = expf(r[i] - m); s += ex[i]; }
    s += __shfl_xor(s, 16);
    s += __shfl_xor(s, 32);

    float pr[16];
#pragma unroll
    for (int i = 0; i < 16; ++i) pr[i] = ex[i] / s;

    uint64_t prev = ~0ull;
    float ovals[8]; float oidx[8];
    float prevp = 0.f; int nearf = 0;
#pragma unroll
    for (int p = 0; p < 8; ++p) {
        uint64_t best = 0;
#pragma unroll
        for (int i = 0; i < 16; ++i) {
            uint64_t key = ((uint64_t)__float_as_uint(pr[i]) << 32)
                         | (uint64_t)(63 - (sub * 16 + i));
            if (key < prev && key > best) best = key;
        }
        {
            uint32_t bh = (uint32_t)(best >> 32), bl = (uint32_t)best;
            uint32_t oh = __shfl_xor(bh, 16), ol = __shfl_xor(bl, 16);
            uint64_t ob = ((uint64_t)oh << 32) | ol;
            if (ob > best) best = ob;
            bh = (uint32_t)(best >> 32); bl = (uint32_t)best;
            oh = __shfl_xor(bh, 32); ol = __shfl_xor(bl, 32);
            ob = ((uint64_t)oh << 32) | ol;
            if (ob > best) best = ob;
        }
        prev = best;
        float pv = __uint_as_float((uint32_t)(best >> 32));
        if (p > 0 && (prevp - pv) < TAU * pv) nearf = 1;
        prevp = pv;
        ovals[p] = pv;
        oidx[p]  = (float)(63 - (int)(best & 63));
    }
    {
        uint64_t best = 0;
#pragma unroll
        for (int i = 0; i < 16; ++i) {
            uint64_t key = ((uint64_t)__float_as_uint(pr[i]) << 32)
                         | (uint64_t)(63 - (sub * 16 + i));
            if (key < prev && key > best) best = key;
        }
        {
            uint32_t bh = (uint32_t)(best >> 32), bl = (uint32_t)best;
            uint32_t oh = __shfl_xor(bh, 16), ol = __shfl_xor(bl, 16);
            uint64_t ob = ((uint64_t)oh << 32) | ol;
            if (ob > best) best = ob;
            bh = (uint32_t)(best >> 32); bl = (uint32_t)best;
            oh = __shfl_xor(bh, 32); ol = __shfl_xor(bl, 32);
            ob = ((uint64_t)oh << 32) | ol;
            if (ob > best) best = ob;
        }
        float pv9 = __uint_as_float((uint32_t)(best >> 32));
        if ((prevp - pv9) < TAU * pv9) nearf = 1;
    }

    if (sub == 0) {
        size_t gtok = (size_t)(t0 + tok);
        float* vo = out + gtok * 8;
        float* io = out + (size_t)ntok * 8 + gtok * 8;
        *(float4*)(vo)     = make_float4(ovals[0], ovals[1], ovals[2], ovals[3]);
        *(float4*)(vo + 4) = make_float4(ovals[4], ovals[5], ovals[6], ovals[7]);
        *(float4*)(io)     = make_float4(oidx[0], oidx[1], oidx[2], oidx[3]);
        *(float4*)(io + 4) = make_float4(oidx[4], oidx[5], oidx[6], oidx[7]);
        flags[gtok] = (unsigned char)nearf;
    }
}

// ------- Pass 2: f64 refinement, 1 wave/token, no LDS, no barriers (R6/R7 verbatim) -------
__global__ __launch_bounds__(64) void moe_gate_refine_kernel(
    const float* __restrict__ x, const float* __restrict__ wgt,
    float* __restrict__ out, int ntok, const unsigned char* __restrict__ flags)
{
    const int lane = threadIdx.x;        // expert id 0..63
    const int base = blockIdx.x * 4;

    for (int t = 0; t < 4; ++t) {
        const int tok = base + t;
        if (flags[tok] == 0) continue;   // wave-uniform

        const float* xp = x   + (size_t)tok  * DIM;
        const float* wp = wgt + (size_t)lane * DIM;
        double acc = 0.0;
        for (int k = 0; k < DIM; k += 4) {
            float4 xv = *(const float4*)(xp + k);
            float4 wv = *(const float4*)(wp + k);
            acc = fma((double)xv.x, (double)wv.x, acc);
            acc = fma((double)xv.y, (double)wv.y, acc);
            acc = fma((double)xv.z, (double)wv.z, acc);
            acc = fma((double)xv.w, (double)wv.w, acc);
        }

        uint64_t mykey = (mono64(acc) & ~63ull) | (uint64_t)(63 - lane);

        uint64_t mk = mykey;
        {
            unsigned long long o;
            o = __shfl_xor((unsigned long long)mk, 1);  if ((uint64_t)o > mk) mk = (uint64_t)o;
            o = __shfl_xor((unsigned long long)mk, 2);  if ((uint64_t)o > mk) mk = (uint64_t)o;
            o = __shfl_xor((unsigned long long)mk, 4);  if ((uint64_t)o > mk) mk = (uint64_t)o;
            o = __shfl_xor((unsigned long long)mk, 8);  if ((uint64_t)o > mk) mk = (uint64_t)o;
            o = __shfl_xor((unsigned long long)mk, 16); if ((uint64_t)o > mk) mk = (uint64_t)o;
            o = __shfl_xor((unsigned long long)mk, 32); if ((uint64_t)o > mk) mk = (uint64_t)o;
        }
        double md = unmono64(mk & ~63ull);

        float s = expf((float)(acc - md));
        s += __shfl_xor(s, 1);
        s += __shfl_xor(s, 2);
        s += __shfl_xor(s, 4);
        s += __shfl_xor(s, 8);
        s += __shfl_xor(s, 16);
        s += __shfl_xor(s, 32);

        float* vo = out + (size_t)tok * 8;
        float* io = out + (size_t)ntok * 8 + (size_t)tok * 8;

        uint64_t prev = ~0ull;
        for (int q = 0; q < 8; ++q) {
            uint64_t best = (mykey < prev) ? mykey : 0;
            {
                unsigned long long o;
                o = __shfl_xor((unsigned long long)best, 1);  if ((uint64_t)o > best) best = (uint64_t)o;
                o = __shfl_xor((unsigned long long)best, 2);  if ((uint64_t)o > best) best = (uint64_t)o;
                o = __shfl_xor((unsigned long long)best, 4);  if ((uint64_t)o > best) best = (uint64_t)o;
                o = __shfl_xor((unsigned long long)best, 8);  if ((uint64_t)o > best) best = (uint64_t)o;
                o = __shfl_xor((unsigned long long)best, 16); if ((uint64_t)o > best) best = (uint64_t)o;
                o = __shfl_xor((unsigned long long)best, 32); if ((uint64_t)o > best) best = (uint64_t)o;
            }
            prev = best;
            if (lane == 0) {
                vo[q] = expf((float)(unmono64(best & ~63ull) - md)) / s;
                io[q] = (float)(63 - (int)(best & 63ull));
            }
        }
    }
}

extern "C" void kernel_launch(void* const* d_in, const int* in_sizes, int n_in,
                              void* d_out, int out_size, void* d_ws, size_t ws_size,
                              hipStream_t stream) {
    const float* x   = (const float*)d_in[0];
    const float* wgt = (const float*)d_in[1];
    float* out = (float*)d_out;
    const int ntok = in_sizes[0] / DIM;   // 32768

    unsigned short* wf   = (unsigned short*)d_ws;                    // 512 KB
    unsigned char*  flags = (unsigned char*)d_ws + FLAGS_OFF;        // ntok bytes

    hipLaunchKernelGGL(wsplit_kernel, dim3(64), dim3(256), 0, stream, wgt, wf);
    hipLaunchKernelGGL(moe_gate_mfma_kernel, dim3(ntok / 16), dim3(64), 0, stream,
                       x, wf, out, ntok, flags);
    hipLaunchKernelGGL(moe_gate_refine_kernel, dim3(ntok / 4), dim3(64), 0, stream,
                       x, wgt, out, ntok, flags);
}

// Round 9
// 198.996 us; speedup vs baseline: 1.1016x; 1.1016x over previous
//
#include <hip/hip_runtime.h>
#include <stdint.h>

#define DIM     2048
#define NEXP    64
#define NCHUNK  32        // K chunks of 64
#define TAU     2e-4f     // near-tie threshold on relative prob gaps

#define WFRAG_USHORTS (NCHUNK * 8192)        // 512 KB fragment image
#define FLAGS_OFF     (WFRAG_USHORTS * 2)    // byte offset of flags in d_ws

typedef __attribute__((ext_vector_type(8))) short bf16x8;
typedef __attribute__((ext_vector_type(8))) unsigned short u16x8;
typedef __attribute__((ext_vector_type(4))) float f32x4;

__device__ inline unsigned short bf16_rne(float f) {
    uint32_t u = __float_as_uint(f);
    return (unsigned short)((u + 0x7FFFu + ((u >> 16) & 1u)) >> 16);
}
__device__ inline float bf16_to_f(unsigned short h) {
    return __uint_as_float(((uint32_t)h) << 16);
}
__device__ inline uint64_t mono64(double d) {
    uint64_t u = (uint64_t)__double_as_longlong(d);
    return (u >> 63) ? ~u : (u | 0x8000000000000000ull);
}
__device__ inline double unmono64(uint64_t m) {
    uint64_t b = (m >> 63) ? (m & 0x7fffffffffffffffull) : ~m;
    return __longlong_as_double((long long)b);
}

#define SPL(F, HV, LV, J)  { unsigned short _h = bf16_rne(F); HV[J] = _h; LV[J] = bf16_rne((F) - bf16_to_f(_h)); }
#define SPLS(F, HV, LV, J) { unsigned short _h = bf16_rne(F); HV[J] = (short)_h; LV[J] = (short)bf16_rne((F) - bf16_to_f(_h)); }

// ---- Kernel 0: split w into bf16 hi/lo B-fragment image ----
// layout (ushort): [c:32][ks:2][t:4][plane:2][lane:64][j:8]
__global__ __launch_bounds__(256) void wsplit_kernel(
    const float* __restrict__ wgt, unsigned short* __restrict__ wf)
{
    int g = blockIdx.x * 256 + threadIdx.x;   // 0..16383 = c*512 + s*256 + t*64 + l
    int l = g & 63;
    int t = (g >> 6) & 3;
    int s = (g >> 8) & 1;
    int c = g >> 9;
    int e = (l & 15) + 16 * t;
    int k = c * 64 + s * 32 + ((l >> 4) * 8);
    const float* wp = wgt + (size_t)e * DIM + k;
    float4 f0 = *(const float4*)(wp);
    float4 f1 = *(const float4*)(wp + 4);
    u16x8 h, lo;
    SPL(f0.x, h, lo, 0) SPL(f0.y, h, lo, 1) SPL(f0.z, h, lo, 2) SPL(f0.w, h, lo, 3)
    SPL(f1.x, h, lo, 4) SPL(f1.y, h, lo, 5) SPL(f1.z, h, lo, 6) SPL(f1.w, h, lo, 7)
    size_t base = ((((size_t)(c * 2 + s) * 4 + t) * 2 + 0) * 64 + l) * 8;
    *(u16x8*)(wf + base)       = h;
    *(u16x8*)(wf + base + 512) = lo;   // plane stride = 64*8
}

// ---- Pass 1: bf16x3 MFMA GEMM, K-split x2 across 2 waves + LDS reduce ----
__global__ __launch_bounds__(128, 4) void moe_gate_mfma_kernel(
    const float* __restrict__ x, const unsigned short* __restrict__ wf,
    float* __restrict__ out, int ntok, unsigned char* __restrict__ flags)
{
    __shared__ float red[64][17];                 // wave1 partials, conflict-free stride
    __shared__ __align__(16) float ls[16][68];    // transposed logits

    const int tid  = threadIdx.x;
    const int wave = tid >> 6;                    // 0,1 = K-half
    const int lane = tid & 63;
    const int t0   = blockIdx.x * 16;
    const int l15  = lane & 15;
    const int lg   = lane >> 4;

    const float* xp = x + (size_t)(t0 + l15) * DIM + lg * 8 + wave * 1024;
    const unsigned short* wl = wf + (size_t)wave * 16 * 8192 + lane * 8;

    f32x4 acc0 = {0.f,0.f,0.f,0.f}, acc1 = {0.f,0.f,0.f,0.f};
    f32x4 acc2 = {0.f,0.f,0.f,0.f}, acc3 = {0.f,0.f,0.f,0.f};

    for (int c = 0; c < 16; ++c) {
        const float* xc = xp + c * 64;
        float4 pa0 = *(const float4*)(xc);
        float4 pa1 = *(const float4*)(xc + 4);
        float4 pa2 = *(const float4*)(xc + 32);
        float4 pa3 = *(const float4*)(xc + 36);

        const unsigned short* wc = wl + (size_t)c * 8192;
        // issue all 16 B-fragment loads up front (latency overlap with splits)
        bf16x8 B0h = *(const bf16x8*)(wc + 0);    bf16x8 B0l = *(const bf16x8*)(wc + 512);
        bf16x8 B1h = *(const bf16x8*)(wc + 1024); bf16x8 B1l = *(const bf16x8*)(wc + 1536);
        bf16x8 B2h = *(const bf16x8*)(wc + 2048); bf16x8 B2l = *(const bf16x8*)(wc + 2560);
        bf16x8 B3h = *(const bf16x8*)(wc + 3072); bf16x8 B3l = *(const bf16x8*)(wc + 3584);
        bf16x8 B4h = *(const bf16x8*)(wc + 4096); bf16x8 B4l = *(const bf16x8*)(wc + 4608);
        bf16x8 B5h = *(const bf16x8*)(wc + 5120); bf16x8 B5l = *(const bf16x8*)(wc + 5632);
        bf16x8 B6h = *(const bf16x8*)(wc + 6144); bf16x8 B6l = *(const bf16x8*)(wc + 6656);
        bf16x8 B7h = *(const bf16x8*)(wc + 7168); bf16x8 B7l = *(const bf16x8*)(wc + 7680);

        bf16x8 Ah0, Al0, Ah1, Al1;
        SPLS(pa0.x, Ah0, Al0, 0) SPLS(pa0.y, Ah0, Al0, 1) SPLS(pa0.z, Ah0, Al0, 2) SPLS(pa0.w, Ah0, Al0, 3)
        SPLS(pa1.x, Ah0, Al0, 4) SPLS(pa1.y, Ah0, Al0, 5) SPLS(pa1.z, Ah0, Al0, 6) SPLS(pa1.w, Ah0, Al0, 7)
        SPLS(pa2.x, Ah1, Al1, 0) SPLS(pa2.y, Ah1, Al1, 1) SPLS(pa2.z, Ah1, Al1, 2) SPLS(pa2.w, Ah1, Al1, 3)
        SPLS(pa3.x, Ah1, Al1, 4) SPLS(pa3.y, Ah1, Al1, 5) SPLS(pa3.z, Ah1, Al1, 6) SPLS(pa3.w, Ah1, Al1, 7)

        // ks = 0
        acc0 = __builtin_amdgcn_mfma_f32_16x16x32_bf16(Ah0, B0h, acc0, 0, 0, 0);
        acc0 = __builtin_amdgcn_mfma_f32_16x16x32_bf16(Ah0, B0l, acc0, 0, 0, 0);
        acc0 = __builtin_amdgcn_mfma_f32_16x16x32_bf16(Al0, B0h, acc0, 0, 0, 0);
        acc1 = __builtin_amdgcn_mfma_f32_16x16x32_bf16(Ah0, B1h, acc1, 0, 0, 0);
        acc1 = __builtin_amdgcn_mfma_f32_16x16x32_bf16(Ah0, B1l, acc1, 0, 0, 0);
        acc1 = __builtin_amdgcn_mfma_f32_16x16x32_bf16(Al0, B1h, acc1, 0, 0, 0);
        acc2 = __builtin_amdgcn_mfma_f32_16x16x32_bf16(Ah0, B2h, acc2, 0, 0, 0);
        acc2 = __builtin_amdgcn_mfma_f32_16x16x32_bf16(Ah0, B2l, acc2, 0, 0, 0);
        acc2 = __builtin_amdgcn_mfma_f32_16x16x32_bf16(Al0, B2h, acc2, 0, 0, 0);
        acc3 = __builtin_amdgcn_mfma_f32_16x16x32_bf16(Ah0, B3h, acc3, 0, 0, 0);
        acc3 = __builtin_amdgcn_mfma_f32_16x16x32_bf16(Ah0, B3l, acc3, 0, 0, 0);
        acc3 = __builtin_amdgcn_mfma_f32_16x16x32_bf16(Al0, B3h, acc3, 0, 0, 0);
        // ks = 1
        acc0 = __builtin_amdgcn_mfma_f32_16x16x32_bf16(Ah1, B4h, acc0, 0, 0, 0);
        acc0 = __builtin_amdgcn_mfma_f32_16x16x32_bf16(Ah1, B4l, acc0, 0, 0, 0);
        acc0 = __builtin_amdgcn_mfma_f32_16x16x32_bf16(Al1, B4h, acc0, 0, 0, 0);
        acc1 = __builtin_amdgcn_mfma_f32_16x16x32_bf16(Ah1, B5h, acc1, 0, 0, 0);
        acc1 = __builtin_amdgcn_mfma_f32_16x16x32_bf16(Ah1, B5l, acc1, 0, 0, 0);
        acc1 = __builtin_amdgcn_mfma_f32_16x16x32_bf16(Al1, B5h, acc1, 0, 0, 0);
        acc2 = __builtin_amdgcn_mfma_f32_16x16x32_bf16(Ah1, B6h, acc2, 0, 0, 0);
        acc2 = __builtin_amdgcn_mfma_f32_16x16x32_bf16(Ah1, B6l, acc2, 0, 0, 0);
        acc2 = __builtin_amdgcn_mfma_f32_16x16x32_bf16(Al1, B6h, acc2, 0, 0, 0);
        acc3 = __builtin_amdgcn_mfma_f32_16x16x32_bf16(Ah1, B7h, acc3, 0, 0, 0);
        acc3 = __builtin_amdgcn_mfma_f32_16x16x32_bf16(Ah1, B7l, acc3, 0, 0, 0);
        acc3 = __builtin_amdgcn_mfma_f32_16x16x32_bf16(Al1, B7h, acc3, 0, 0, 0);
    }

    // ---- cross-wave K reduction via LDS ----
    if (wave == 1) {
#pragma unroll
        for (int i = 0; i < 4; ++i) {
            red[lane][ 0 + i] = acc0[i];
            red[lane][ 4 + i] = acc1[i];
            red[lane][ 8 + i] = acc2[i];
            red[lane][12 + i] = acc3[i];
        }
    }
    __syncthreads();
    if (wave == 0) {
#pragma unroll
        for (int i = 0; i < 4; ++i) {
            acc0[i] += red[lane][ 0 + i];
            acc1[i] += red[lane][ 4 + i];
            acc2[i] += red[lane][ 8 + i];
            acc3[i] += red[lane][12 + i];
        }
        const int rb = lg * 4;
        ls[rb + 0][ 0 + l15] = acc0[0]; ls[rb + 1][ 0 + l15] = acc0[1];
        ls[rb + 2][ 0 + l15] = acc0[2]; ls[rb + 3][ 0 + l15] = acc0[3];
        ls[rb + 0][16 + l15] = acc1[0]; ls[rb + 1][16 + l15] = acc1[1];
        ls[rb + 2][16 + l15] = acc1[2]; ls[rb + 3][16 + l15] = acc1[3];
        ls[rb + 0][32 + l15] = acc2[0]; ls[rb + 1][32 + l15] = acc2[1];
        ls[rb + 2][32 + l15] = acc2[2]; ls[rb + 3][32 + l15] = acc2[3];
        ls[rb + 0][48 + l15] = acc3[0]; ls[rb + 1][48 + l15] = acc3[1];
        ls[rb + 2][48 + l15] = acc3[2]; ls[rb + 3][48 + l15] = acc3[3];
    }
    __syncthreads();

    if (wave == 0) {
        // ---- softmax + top-8: 4 lanes per token, 16 experts each (R6/R7/R8 construct) ----
        const int tok = l15;
        const int sub = lg;

        float r[16];
#pragma unroll
        for (int k = 0; k < 4; ++k) {
            float4 v = *(const float4*)(&ls[tok][sub * 16 + 4 * k]);
            r[4 * k] = v.x; r[4 * k + 1] = v.y; r[4 * k + 2] = v.z; r[4 * k + 3] = v.w;
        }

        float m = r[0];
#pragma unroll
        for (int i = 1; i < 16; ++i) m = fmaxf(m, r[i]);
        m = fmaxf(m, __shfl_xor(m, 16));
        m = fmaxf(m, __shfl_xor(m, 32));

        float ex[16]; float s = 0.f;
#pragma unroll
        for (int i = 0; i < 16; ++i) { ex[i] = expf(r[i] - m); s += ex[i]; }
        s += __shfl_xor(s, 16);
        s += __shfl_xor(s, 32);

        float pr[16];
#pragma unroll
        for (int i = 0; i < 16; ++i) pr[i] = ex[i] / s;

        uint64_t prev = ~0ull;
        float ovals[8]; float oidx[8];
        float prevp = 0.f; int nearf = 0;
#pragma unroll
        for (int p = 0; p < 8; ++p) {
            uint64_t best = 0;
#pragma unroll
            for (int i = 0; i < 16; ++i) {
                uint64_t key = ((uint64_t)__float_as_uint(pr[i]) << 32)
                             | (uint64_t)(63 - (sub * 16 + i));
                if (key < prev && key > best) best = key;
            }
            {
                uint32_t bh = (uint32_t)(best >> 32), bl = (uint32_t)best;
                uint32_t oh = __shfl_xor(bh, 16), ol = __shfl_xor(bl, 16);
                uint64_t ob = ((uint64_t)oh << 32) | ol;
                if (ob > best) best = ob;
                bh = (uint32_t)(best >> 32); bl = (uint32_t)best;
                oh = __shfl_xor(bh, 32); ol = __shfl_xor(bl, 32);
                ob = ((uint64_t)oh << 32) | ol;
                if (ob > best) best = ob;
            }
            prev = best;
            float pv = __uint_as_float((uint32_t)(best >> 32));
            if (p > 0 && (prevp - pv) < TAU * pv) nearf = 1;
            prevp = pv;
            ovals[p] = pv;
            oidx[p]  = (float)(63 - (int)(best & 63));
        }
        {
            uint64_t best = 0;
#pragma unroll
            for (int i = 0; i < 16; ++i) {
                uint64_t key = ((uint64_t)__float_as_uint(pr[i]) << 32)
                             | (uint64_t)(63 - (sub * 16 + i));
                if (key < prev && key > best) best = key;
            }
            {
                uint32_t bh = (uint32_t)(best >> 32), bl = (uint32_t)best;
                uint32_t oh = __shfl_xor(bh, 16), ol = __shfl_xor(bl, 16);
                uint64_t ob = ((uint64_t)oh << 32) | ol;
                if (ob > best) best = ob;
                bh = (uint32_t)(best >> 32); bl = (uint32_t)best;
                oh = __shfl_xor(bh, 32); ol = __shfl_xor(bl, 32);
                ob = ((uint64_t)oh << 32) | ol;
                if (ob > best) best = ob;
            }
            float pv9 = __uint_as_float((uint32_t)(best >> 32));
            if ((prevp - pv9) < TAU * pv9) nearf = 1;
        }

        if (sub == 0) {
            size_t gtok = (size_t)(t0 + tok);
            float* vo = out + gtok * 8;
            float* io = out + (size_t)ntok * 8 + gtok * 8;
            *(float4*)(vo)     = make_float4(ovals[0], ovals[1], ovals[2], ovals[3]);
            *(float4*)(vo + 4) = make_float4(ovals[4], ovals[5], ovals[6], ovals[7]);
            *(float4*)(io)     = make_float4(oidx[0], oidx[1], oidx[2], oidx[3]);
            *(float4*)(io + 4) = make_float4(oidx[4], oidx[5], oidx[6], oidx[7]);
            flags[gtok] = (unsigned char)nearf;
        }
    }
}

// ------- Pass 2: f64 refinement, 1 wave/token, no LDS, no barriers (R6-R8 verbatim) -------
__global__ __launch_bounds__(64) void moe_gate_refine_kernel(
    const float* __restrict__ x, const float* __restrict__ wgt,
    float* __restrict__ out, int ntok, const unsigned char* __restrict__ flags)
{
    const int lane = threadIdx.x;        // expert id 0..63
    const int base = blockIdx.x * 4;

    for (int t = 0; t < 4; ++t) {
        const int tok = base + t;
        if (flags[tok] == 0) continue;   // wave-uniform

        const float* xp = x   + (size_t)tok  * DIM;
        const float* wp = wgt + (size_t)lane * DIM;
        double acc = 0.0;
        for (int k = 0; k < DIM; k += 4) {
            float4 xv = *(const float4*)(xp + k);
            float4 wv = *(const float4*)(wp + k);
            acc = fma((double)xv.x, (double)wv.x, acc);
            acc = fma((double)xv.y, (double)wv.y, acc);
            acc = fma((double)xv.z, (double)wv.z, acc);
            acc = fma((double)xv.w, (double)wv.w, acc);
        }

        uint64_t mykey = (mono64(acc) & ~63ull) | (uint64_t)(63 - lane);

        uint64_t mk = mykey;
        {
            unsigned long long o;
            o = __shfl_xor((unsigned long long)mk, 1);  if ((uint64_t)o > mk) mk = (uint64_t)o;
            o = __shfl_xor((unsigned long long)mk, 2);  if ((uint64_t)o > mk) mk = (uint64_t)o;
            o = __shfl_xor((unsigned long long)mk, 4);  if ((uint64_t)o > mk) mk = (uint64_t)o;
            o = __shfl_xor((unsigned long long)mk, 8);  if ((uint64_t)o > mk) mk = (uint64_t)o;
            o = __shfl_xor((unsigned long long)mk, 16); if ((uint64_t)o > mk) mk = (uint64_t)o;
            o = __shfl_xor((unsigned long long)mk, 32); if ((uint64_t)o > mk) mk = (uint64_t)o;
        }
        double md = unmono64(mk & ~63ull);

        float s = expf((float)(acc - md));
        s += __shfl_xor(s, 1);
        s += __shfl_xor(s, 2);
        s += __shfl_xor(s, 4);
        s += __shfl_xor(s, 8);
        s += __shfl_xor(s, 16);
        s += __shfl_xor(s, 32);

        float* vo = out + (size_t)tok * 8;
        float* io = out + (size_t)ntok * 8 + (size_t)tok * 8;

        uint64_t prev = ~0ull;
        for (int q = 0; q < 8; ++q) {
            uint64_t best = (mykey < prev) ? mykey : 0;
            {
                unsigned long long o;
                o = __shfl_xor((unsigned long long)best, 1);  if ((uint64_t)o > best) best = (uint64_t)o;
                o = __shfl_xor((unsigned long long)best, 2);  if ((uint64_t)o > best) best = (uint64_t)o;
                o = __shfl_xor((unsigned long long)best, 4);  if ((uint64_t)o > best) best = (uint64_t)o;
                o = __shfl_xor((unsigned long long)best, 8);  if ((uint64_t)o > best) best = (uint64_t)o;
                o = __shfl_xor((unsigned long long)best, 16); if ((uint64_t)o > best) best = (uint64_t)o;
                o = __shfl_xor((unsigned long long)best, 32); if ((uint64_t)o > best) best = (uint64_t)o;
            }
            prev = best;
            if (lane == 0) {
                vo[q] = expf((float)(unmono64(best & ~63ull) - md)) / s;
                io[q] = (float)(63 - (int)(best & 63ull));
            }
        }
    }
}

extern "C" void kernel_launch(void* const* d_in, const int* in_sizes, int n_in,
                              void* d_out, int out_size, void* d_ws, size_t ws_size,
                              hipStream_t stream) {
    const float* x   = (const float*)d_in[0];
    const float* wgt = (const float*)d_in[1];
    float* out = (float*)d_out;
    const int ntok = in_sizes[0] / DIM;   // 32768

    unsigned short* wf    = (unsigned short*)d_ws;                   // 512 KB
    unsigned char*  flags = (unsigned char*)d_ws + FLAGS_OFF;        // ntok bytes

    hipLaunchKernelGGL(wsplit_kernel, dim3(64), dim3(256), 0, stream, wgt, wf);
    hipLaunchKernelGGL(moe_gate_mfma_kernel, dim3(ntok / 16), dim3(128), 0, stream,
                       x, wf, out, ntok, flags);
    hipLaunchKernelGGL(moe_gate_refine_kernel, dim3(ntok / 4), dim3(64), 0, stream,
                       x, wgt, out, ntok, flags);
}

// Round 10
// 195.326 us; speedup vs baseline: 1.1223x; 1.0188x over previous
//
#include <hip/hip_runtime.h>
#include <stdint.h>

#define DIM     2048
#define NEXP    64
#define NCHUNK  32        // K chunks of 64
#define TAU     2e-4f     // near-tie threshold on relative prob gaps

#define WFRAG_USHORTS (NCHUNK * 8192)        // 512 KB fragment image
#define FLAGS_OFF     (WFRAG_USHORTS * 2)    // byte offset of flags in d_ws

typedef __attribute__((ext_vector_type(8))) short bf16x8;
typedef __attribute__((ext_vector_type(8))) unsigned short u16x8;
typedef __attribute__((ext_vector_type(4))) float f32x4;

__device__ inline unsigned short bf16_rne(float f) {
    uint32_t u = __float_as_uint(f);
    return (unsigned short)((u + 0x7FFFu + ((u >> 16) & 1u)) >> 16);
}
__device__ inline float bf16_to_f(unsigned short h) {
    return __uint_as_float(((uint32_t)h) << 16);
}
__device__ inline uint64_t mono64(double d) {
    uint64_t u = (uint64_t)__double_as_longlong(d);
    return (u >> 63) ? ~u : (u | 0x8000000000000000ull);
}
__device__ inline double unmono64(uint64_t m) {
    uint64_t b = (m >> 63) ? (m & 0x7fffffffffffffffull) : ~m;
    return __longlong_as_double((long long)b);
}

#define SPL(F, HV, LV, J)  { unsigned short _h = bf16_rne(F); HV[J] = _h; LV[J] = bf16_rne((F) - bf16_to_f(_h)); }
#define SPLS(F, HV, LV, J) { unsigned short _h = bf16_rne(F); HV[J] = (short)_h; LV[J] = (short)bf16_rne((F) - bf16_to_f(_h)); }

// ---- Kernel 0: split w into bf16 hi/lo B-fragment image ----
// layout (ushort): [c:32][ks:2][t:4][plane:2][lane:64][j:8]
__global__ __launch_bounds__(256) void wsplit_kernel(
    const float* __restrict__ wgt, unsigned short* __restrict__ wf)
{
    int g = blockIdx.x * 256 + threadIdx.x;   // 0..16383 = c*512 + s*256 + t*64 + l
    int l = g & 63;
    int t = (g >> 6) & 3;
    int s = (g >> 8) & 1;
    int c = g >> 9;
    int e = (l & 15) + 16 * t;
    int k = c * 64 + s * 32 + ((l >> 4) * 8);
    const float* wp = wgt + (size_t)e * DIM + k;
    float4 f0 = *(const float4*)(wp);
    float4 f1 = *(const float4*)(wp + 4);
    u16x8 h, lo;
    SPL(f0.x, h, lo, 0) SPL(f0.y, h, lo, 1) SPL(f0.z, h, lo, 2) SPL(f0.w, h, lo, 3)
    SPL(f1.x, h, lo, 4) SPL(f1.y, h, lo, 5) SPL(f1.z, h, lo, 6) SPL(f1.w, h, lo, 7)
    size_t base = ((((size_t)(c * 2 + s) * 4 + t) * 2 + 0) * 64 + l) * 8;
    *(u16x8*)(wf + base)       = h;
    *(u16x8*)(wf + base + 512) = lo;   // plane stride = 64*8
}

// ---- Pass 1: bf16x3 MFMA GEMM, K-split x2 across 2 waves, grouped B loads ----
__global__ __launch_bounds__(128, 4) void moe_gate_mfma_kernel(
    const float* __restrict__ x, const unsigned short* __restrict__ wf,
    float* __restrict__ out, int ntok, unsigned char* __restrict__ flags)
{
    __shared__ float red[64][17];                 // wave1 partials, conflict-free stride
    __shared__ __align__(16) float ls[16][68];    // transposed logits

    const int tid  = threadIdx.x;
    const int wave = tid >> 6;                    // 0,1 = K-half
    const int lane = tid & 63;
    const int t0   = blockIdx.x * 16;
    const int l15  = lane & 15;
    const int lg   = lane >> 4;

    const float* xp = x + (size_t)(t0 + l15) * DIM + lg * 8 + wave * 1024;
    const unsigned short* wl = wf + (size_t)wave * 16 * 8192 + lane * 8;

    f32x4 acc0 = {0.f,0.f,0.f,0.f}, acc1 = {0.f,0.f,0.f,0.f};
    f32x4 acc2 = {0.f,0.f,0.f,0.f}, acc3 = {0.f,0.f,0.f,0.f};

    float4 pa0 = *(const float4*)(xp);
    float4 pa1 = *(const float4*)(xp + 4);
    float4 pa2 = *(const float4*)(xp + 32);
    float4 pa3 = *(const float4*)(xp + 36);

    for (int c = 0; c < 16; ++c) {
        float4 pb0 = pa0, pb1 = pa1, pb2 = pa2, pb3 = pa3;
        if (c < 15) {
            const float* xn = xp + (c + 1) * 64;
            pb0 = *(const float4*)(xn);
            pb1 = *(const float4*)(xn + 4);
            pb2 = *(const float4*)(xn + 32);
            pb3 = *(const float4*)(xn + 36);
        }

        bf16x8 Ah0, Al0, Ah1, Al1;
        SPLS(pa0.x, Ah0, Al0, 0) SPLS(pa0.y, Ah0, Al0, 1) SPLS(pa0.z, Ah0, Al0, 2) SPLS(pa0.w, Ah0, Al0, 3)
        SPLS(pa1.x, Ah0, Al0, 4) SPLS(pa1.y, Ah0, Al0, 5) SPLS(pa1.z, Ah0, Al0, 6) SPLS(pa1.w, Ah0, Al0, 7)
        SPLS(pa2.x, Ah1, Al1, 0) SPLS(pa2.y, Ah1, Al1, 1) SPLS(pa2.z, Ah1, Al1, 2) SPLS(pa2.w, Ah1, Al1, 3)
        SPLS(pa3.x, Ah1, Al1, 4) SPLS(pa3.y, Ah1, Al1, 5) SPLS(pa3.z, Ah1, Al1, 6) SPLS(pa3.w, Ah1, Al1, 7)

        const unsigned short* wc = wl + (size_t)c * 8192;
        // tile 0: acc0  (ks0 at +0, ks1 at +4096)
        {
            bf16x8 Bh0 = *(const bf16x8*)(wc + 0);
            bf16x8 Bl0 = *(const bf16x8*)(wc + 512);
            bf16x8 Bh1 = *(const bf16x8*)(wc + 4096);
            bf16x8 Bl1 = *(const bf16x8*)(wc + 4608);
            acc0 = __builtin_amdgcn_mfma_f32_16x16x32_bf16(Ah0, Bh0, acc0, 0, 0, 0);
            acc0 = __builtin_amdgcn_mfma_f32_16x16x32_bf16(Ah0, Bl0, acc0, 0, 0, 0);
            acc0 = __builtin_amdgcn_mfma_f32_16x16x32_bf16(Al0, Bh0, acc0, 0, 0, 0);
            acc0 = __builtin_amdgcn_mfma_f32_16x16x32_bf16(Ah1, Bh1, acc0, 0, 0, 0);
            acc0 = __builtin_amdgcn_mfma_f32_16x16x32_bf16(Ah1, Bl1, acc0, 0, 0, 0);
            acc0 = __builtin_amdgcn_mfma_f32_16x16x32_bf16(Al1, Bh1, acc0, 0, 0, 0);
        }
        // tile 1: acc1
        {
            bf16x8 Bh0 = *(const bf16x8*)(wc + 1024);
            bf16x8 Bl0 = *(const bf16x8*)(wc + 1536);
            bf16x8 Bh1 = *(const bf16x8*)(wc + 5120);
            bf16x8 Bl1 = *(const bf16x8*)(wc + 5632);
            acc1 = __builtin_amdgcn_mfma_f32_16x16x32_bf16(Ah0, Bh0, acc1, 0, 0, 0);
            acc1 = __builtin_amdgcn_mfma_f32_16x16x32_bf16(Ah0, Bl0, acc1, 0, 0, 0);
            acc1 = __builtin_amdgcn_mfma_f32_16x16x32_bf16(Al0, Bh0, acc1, 0, 0, 0);
            acc1 = __builtin_amdgcn_mfma_f32_16x16x32_bf16(Ah1, Bh1, acc1, 0, 0, 0);
            acc1 = __builtin_amdgcn_mfma_f32_16x16x32_bf16(Ah1, Bl1, acc1, 0, 0, 0);
            acc1 = __builtin_amdgcn_mfma_f32_16x16x32_bf16(Al1, Bh1, acc1, 0, 0, 0);
        }
        // tile 2: acc2
        {
            bf16x8 Bh0 = *(const bf16x8*)(wc + 2048);
            bf16x8 Bl0 = *(const bf16x8*)(wc + 2560);
            bf16x8 Bh1 = *(const bf16x8*)(wc + 6144);
            bf16x8 Bl1 = *(const bf16x8*)(wc + 6656);
            acc2 = __builtin_amdgcn_mfma_f32_16x16x32_bf16(Ah0, Bh0, acc2, 0, 0, 0);
            acc2 = __builtin_amdgcn_mfma_f32_16x16x32_bf16(Ah0, Bl0, acc2, 0, 0, 0);
            acc2 = __builtin_amdgcn_mfma_f32_16x16x32_bf16(Al0, Bh0, acc2, 0, 0, 0);
            acc2 = __builtin_amdgcn_mfma_f32_16x16x32_bf16(Ah1, Bh1, acc2, 0, 0, 0);
            acc2 = __builtin_amdgcn_mfma_f32_16x16x32_bf16(Ah1, Bl1, acc2, 0, 0, 0);
            acc2 = __builtin_amdgcn_mfma_f32_16x16x32_bf16(Al1, Bh1, acc2, 0, 0, 0);
        }
        // tile 3: acc3
        {
            bf16x8 Bh0 = *(const bf16x8*)(wc + 3072);
            bf16x8 Bl0 = *(const bf16x8*)(wc + 3584);
            bf16x8 Bh1 = *(const bf16x8*)(wc + 7168);
            bf16x8 Bl1 = *(const bf16x8*)(wc + 7680);
            acc3 = __builtin_amdgcn_mfma_f32_16x16x32_bf16(Ah0, Bh0, acc3, 0, 0, 0);
            acc3 = __builtin_amdgcn_mfma_f32_16x16x32_bf16(Ah0, Bl0, acc3, 0, 0, 0);
            acc3 = __builtin_amdgcn_mfma_f32_16x16x32_bf16(Al0, Bh0, acc3, 0, 0, 0);
            acc3 = __builtin_amdgcn_mfma_f32_16x16x32_bf16(Ah1, Bh1, acc3, 0, 0, 0);
            acc3 = __builtin_amdgcn_mfma_f32_16x16x32_bf16(Ah1, Bl1, acc3, 0, 0, 0);
            acc3 = __builtin_amdgcn_mfma_f32_16x16x32_bf16(Al1, Bh1, acc3, 0, 0, 0);
        }

        pa0 = pb0; pa1 = pb1; pa2 = pb2; pa3 = pb3;
    }

    // ---- cross-wave K reduction via LDS ----
    if (wave == 1) {
#pragma unroll
        for (int i = 0; i < 4; ++i) {
            red[lane][ 0 + i] = acc0[i];
            red[lane][ 4 + i] = acc1[i];
            red[lane][ 8 + i] = acc2[i];
            red[lane][12 + i] = acc3[i];
        }
    }
    __syncthreads();
    if (wave == 0) {
#pragma unroll
        for (int i = 0; i < 4; ++i) {
            acc0[i] += red[lane][ 0 + i];
            acc1[i] += red[lane][ 4 + i];
            acc2[i] += red[lane][ 8 + i];
            acc3[i] += red[lane][12 + i];
        }
        const int rb = lg * 4;
        ls[rb + 0][ 0 + l15] = acc0[0]; ls[rb + 1][ 0 + l15] = acc0[1];
        ls[rb + 2][ 0 + l15] = acc0[2]; ls[rb + 3][ 0 + l15] = acc0[3];
        ls[rb + 0][16 + l15] = acc1[0]; ls[rb + 1][16 + l15] = acc1[1];
        ls[rb + 2][16 + l15] = acc1[2]; ls[rb + 3][16 + l15] = acc1[3];
        ls[rb + 0][32 + l15] = acc2[0]; ls[rb + 1][32 + l15] = acc2[1];
        ls[rb + 2][32 + l15] = acc2[2]; ls[rb + 3][32 + l15] = acc2[3];
        ls[rb + 0][48 + l15] = acc3[0]; ls[rb + 1][48 + l15] = acc3[1];
        ls[rb + 2][48 + l15] = acc3[2]; ls[rb + 3][48 + l15] = acc3[3];
    }
    __syncthreads();

    if (wave == 0) {
        // ---- softmax + top-8: 4 lanes per token, 16 experts each (R6-R9 construct) ----
        const int tok = l15;
        const int sub = lg;

        float r[16];
#pragma unroll
        for (int k = 0; k < 4; ++k) {
            float4 v = *(const float4*)(&ls[tok][sub * 16 + 4 * k]);
            r[4 * k] = v.x; r[4 * k + 1] = v.y; r[4 * k + 2] = v.z; r[4 * k + 3] = v.w;
        }

        float m = r[0];
#pragma unroll
        for (int i = 1; i < 16; ++i) m = fmaxf(m, r[i]);
        m = fmaxf(m, __shfl_xor(m, 16));
        m = fmaxf(m, __shfl_xor(m, 32));

        float ex[16]; float s = 0.f;
#pragma unroll
        for (int i = 0; i < 16; ++i) { ex[i] = expf(r[i] - m); s += ex[i]; }
        s += __shfl_xor(s, 16);
        s += __shfl_xor(s, 32);

        float pr[16];
#pragma unroll
        for (int i = 0; i < 16; ++i) pr[i] = ex[i] / s;

        uint64_t prev = ~0ull;
        float ovals[8]; float oidx[8];
        float prevp = 0.f; int nearf = 0;
#pragma unroll
        for (int p = 0; p < 8; ++p) {
            uint64_t best = 0;
#pragma unroll
            for (int i = 0; i < 16; ++i) {
                uint64_t key = ((uint64_t)__float_as_uint(pr[i]) << 32)
                             | (uint64_t)(63 - (sub * 16 + i));
                if (key < prev && key > best) best = key;
            }
            {
                uint32_t bh = (uint32_t)(best >> 32), bl = (uint32_t)best;
                uint32_t oh = __shfl_xor(bh, 16), ol = __shfl_xor(bl, 16);
                uint64_t ob = ((uint64_t)oh << 32) | ol;
                if (ob > best) best = ob;
                bh = (uint32_t)(best >> 32); bl = (uint32_t)best;
                oh = __shfl_xor(bh, 32); ol = __shfl_xor(bl, 32);
                ob = ((uint64_t)oh << 32) | ol;
                if (ob > best) best = ob;
            }
            prev = best;
            float pv = __uint_as_float((uint32_t)(best >> 32));
            if (p > 0 && (prevp - pv) < TAU * pv) nearf = 1;
            prevp = pv;
            ovals[p] = pv;
            oidx[p]  = (float)(63 - (int)(best & 63));
        }
        {
            uint64_t best = 0;
#pragma unroll
            for (int i = 0; i < 16; ++i) {
                uint64_t key = ((uint64_t)__float_as_uint(pr[i]) << 32)
                             | (uint64_t)(63 - (sub * 16 + i));
                if (key < prev && key > best) best = key;
            }
            {
                uint32_t bh = (uint32_t)(best >> 32), bl = (uint32_t)best;
                uint32_t oh = __shfl_xor(bh, 16), ol = __shfl_xor(bl, 16);
                uint64_t ob = ((uint64_t)oh << 32) | ol;
                if (ob > best) best = ob;
                bh = (uint32_t)(best >> 32); bl = (uint32_t)best;
                oh = __shfl_xor(bh, 32); ol = __shfl_xor(bl, 32);
                ob = ((uint64_t)oh << 32) | ol;
                if (ob > best) best = ob;
            }
            float pv9 = __uint_as_float((uint32_t)(best >> 32));
            if ((prevp - pv9) < TAU * pv9) nearf = 1;
        }

        if (sub == 0) {
            size_t gtok = (size_t)(t0 + tok);
            float* vo = out + gtok * 8;
            float* io = out + (size_t)ntok * 8 + gtok * 8;
            *(float4*)(vo)     = make_float4(ovals[0], ovals[1], ovals[2], ovals[3]);
            *(float4*)(vo + 4) = make_float4(ovals[4], ovals[5], ovals[6], ovals[7]);
            *(float4*)(io)     = make_float4(oidx[0], oidx[1], oidx[2], oidx[3]);
            *(float4*)(io + 4) = make_float4(oidx[4], oidx[5], oidx[6], oidx[7]);
            flags[gtok] = (unsigned char)nearf;
        }
    }
}

// ------- Pass 2: f64 refinement, 1 wave/token, no LDS, no barriers (4-wide acc) -------
__global__ __launch_bounds__(64) void moe_gate_refine_kernel(
    const float* __restrict__ x, const float* __restrict__ wgt,
    float* __restrict__ out, int ntok, const unsigned char* __restrict__ flags)
{
    const int lane = threadIdx.x;        // expert id 0..63
    const int base = blockIdx.x * 4;

    for (int t = 0; t < 4; ++t) {
        const int tok = base + t;
        if (flags[tok] == 0) continue;   // wave-uniform

        const float* xp = x   + (size_t)tok  * DIM;
        const float* wp = wgt + (size_t)lane * DIM;
        double a0 = 0.0, a1 = 0.0, a2 = 0.0, a3 = 0.0;
        for (int k = 0; k < DIM; k += 16) {
            float4 xv0 = *(const float4*)(xp + k);
            float4 wv0 = *(const float4*)(wp + k);
            float4 xv1 = *(const float4*)(xp + k + 4);
            float4 wv1 = *(const float4*)(wp + k + 4);
            float4 xv2 = *(const float4*)(xp + k + 8);
            float4 wv2 = *(const float4*)(wp + k + 8);
            float4 xv3 = *(const float4*)(xp + k + 12);
            float4 wv3 = *(const float4*)(wp + k + 12);
            a0 = fma((double)xv0.x, (double)wv0.x, a0);
            a0 = fma((double)xv0.y, (double)wv0.y, a0);
            a0 = fma((double)xv0.z, (double)wv0.z, a0);
            a0 = fma((double)xv0.w, (double)wv0.w, a0);
            a1 = fma((double)xv1.x, (double)wv1.x, a1);
            a1 = fma((double)xv1.y, (double)wv1.y, a1);
            a1 = fma((double)xv1.z, (double)wv1.z, a1);
            a1 = fma((double)xv1.w, (double)wv1.w, a1);
            a2 = fma((double)xv2.x, (double)wv2.x, a2);
            a2 = fma((double)xv2.y, (double)wv2.y, a2);
            a2 = fma((double)xv2.z, (double)wv2.z, a2);
            a2 = fma((double)xv2.w, (double)wv2.w, a2);
            a3 = fma((double)xv3.x, (double)wv3.x, a3);
            a3 = fma((double)xv3.y, (double)wv3.y, a3);
            a3 = fma((double)xv3.z, (double)wv3.z, a3);
            a3 = fma((double)xv3.w, (double)wv3.w, a3);
        }
        double acc = (a0 + a1) + (a2 + a3);

        uint64_t mykey = (mono64(acc) & ~63ull) | (uint64_t)(63 - lane);

        uint64_t mk = mykey;
        {
            unsigned long long o;
            o = __shfl_xor((unsigned long long)mk, 1);  if ((uint64_t)o > mk) mk = (uint64_t)o;
            o = __shfl_xor((unsigned long long)mk, 2);  if ((uint64_t)o > mk) mk = (uint64_t)o;
            o = __shfl_xor((unsigned long long)mk, 4);  if ((uint64_t)o > mk) mk = (uint64_t)o;
            o = __shfl_xor((unsigned long long)mk, 8);  if ((uint64_t)o > mk) mk = (uint64_t)o;
            o = __shfl_xor((unsigned long long)mk, 16); if ((uint64_t)o > mk) mk = (uint64_t)o;
            o = __shfl_xor((unsigned long long)mk, 32); if ((uint64_t)o > mk) mk = (uint64_t)o;
        }
        double md = unmono64(mk & ~63ull);

        float s = expf((float)(acc - md));
        s += __shfl_xor(s, 1);
        s += __shfl_xor(s, 2);
        s += __shfl_xor(s, 4);
        s += __shfl_xor(s, 8);
        s += __shfl_xor(s, 16);
        s += __shfl_xor(s, 32);

        float* vo = out + (size_t)tok * 8;
        float* io = out + (size_t)ntok * 8 + (size_t)tok * 8;

        uint64_t prev = ~0ull;
        for (int q = 0; q < 8; ++q) {
            uint64_t best = (mykey < prev) ? mykey : 0;
            {
                unsigned long long o;
                o = __shfl_xor((unsigned long long)best, 1);  if ((uint64_t)o > best) best = (uint64_t)o;
                o = __shfl_xor((unsigned long long)best, 2);  if ((uint64_t)o > best) best = (uint64_t)o;
                o = __shfl_xor((unsigned long long)best, 4);  if ((uint64_t)o > best) best = (uint64_t)o;
                o = __shfl_xor((unsigned long long)best, 8);  if ((uint64_t)o > best) best = (uint64_t)o;
                o = __shfl_xor((unsigned long long)best, 16); if ((uint64_t)o > best) best = (uint64_t)o;
                o = __shfl_xor((unsigned long long)best, 32); if ((uint64_t)o > best) best = (uint64_t)o;
            }
            prev = best;
            if (lane == 0) {
                vo[q] = expf((float)(unmono64(best & ~63ull) - md)) / s;
                io[q] = (float)(63 - (int)(best & 63ull));
            }
        }
    }
}

extern "C" void kernel_launch(void* const* d_in, const int* in_sizes, int n_in,
                              void* d_out, int out_size, void* d_ws, size_t ws_size,
                              hipStream_t stream) {
    const float* x   = (const float*)d_in[0];
    const float* wgt = (const float*)d_in[1];
    float* out = (float*)d_out;
    const int ntok = in_sizes[0] / DIM;   // 32768

    unsigned short* wf    = (unsigned short*)d_ws;                   // 512 KB
    unsigned char*  flags = (unsigned char*)d_ws + FLAGS_OFF;        // ntok bytes

    hipLaunchKernelGGL(wsplit_kernel, dim3(64), dim3(256), 0, stream, wgt, wf);
    hipLaunchKernelGGL(moe_gate_mfma_kernel, dim3(ntok / 16), dim3(128), 0, stream,
                       x, wf, out, ntok, flags);
    hipLaunchKernelGGL(moe_gate_refine_kernel, dim3(ntok / 4), dim3(64), 0, stream,
                       x, wgt, out, ntok, flags);
}

// Round 11
// 192.443 us; speedup vs baseline: 1.1391x; 1.0150x over previous
//
#include <hip/hip_runtime.h>
#include <stdint.h>

#define DIM     2048
#define NEXP    64
#define NCHUNK  32        // K chunks of 64
#define TAU     2e-4f     // near-tie threshold on relative prob gaps

#define WFRAG_USHORTS (NCHUNK * 8192)        // 512 KB fragment image
#define FLAGS_OFF     (WFRAG_USHORTS * 2)    // byte offset of flags in d_ws

typedef __attribute__((ext_vector_type(8))) short bf16x8;
typedef __attribute__((ext_vector_type(8))) unsigned short u16x8;
typedef __attribute__((ext_vector_type(4))) float f32x4;

__device__ inline unsigned short bf16_rne(float f) {
    uint32_t u = __float_as_uint(f);
    return (unsigned short)((u + 0x7FFFu + ((u >> 16) & 1u)) >> 16);
}
__device__ inline float bf16_to_f(unsigned short h) {
    return __uint_as_float(((uint32_t)h) << 16);
}
__device__ inline uint64_t mono64(double d) {
    uint64_t u = (uint64_t)__double_as_longlong(d);
    return (u >> 63) ? ~u : (u | 0x8000000000000000ull);
}
__device__ inline double unmono64(uint64_t m) {
    uint64_t b = (m >> 63) ? (m & 0x7fffffffffffffffull) : ~m;
    return __longlong_as_double((long long)b);
}

#define SPL(F, HV, LV, J)  { unsigned short _h = bf16_rne(F); HV[J] = _h; LV[J] = bf16_rne((F) - bf16_to_f(_h)); }
#define SPLS(F, HV, LV, J) { unsigned short _h = bf16_rne(F); HV[J] = (short)_h; LV[J] = (short)bf16_rne((F) - bf16_to_f(_h)); }

// ---- Kernel 0: split w into bf16 hi/lo B-fragment image ----
// layout (ushort): [c:32][ks:2][t:4][plane:2][lane:64][j:8]
__global__ __launch_bounds__(256) void wsplit_kernel(
    const float* __restrict__ wgt, unsigned short* __restrict__ wf)
{
    int g = blockIdx.x * 256 + threadIdx.x;   // 0..16383 = c*512 + s*256 + t*64 + l
    int l = g & 63;
    int t = (g >> 6) & 3;
    int s = (g >> 8) & 1;
    int c = g >> 9;
    int e = (l & 15) + 16 * t;
    int k = c * 64 + s * 32 + ((l >> 4) * 8);
    const float* wp = wgt + (size_t)e * DIM + k;
    float4 f0 = *(const float4*)(wp);
    float4 f1 = *(const float4*)(wp + 4);
    u16x8 h, lo;
    SPL(f0.x, h, lo, 0) SPL(f0.y, h, lo, 1) SPL(f0.z, h, lo, 2) SPL(f0.w, h, lo, 3)
    SPL(f1.x, h, lo, 4) SPL(f1.y, h, lo, 5) SPL(f1.z, h, lo, 6) SPL(f1.w, h, lo, 7)
    size_t base = ((((size_t)(c * 2 + s) * 4 + t) * 2 + 0) * 64 + l) * 8;
    *(u16x8*)(wf + base)       = h;
    *(u16x8*)(wf + base + 512) = lo;   // plane stride = 64*8
}

// ---- Pass 1: bf16x3 MFMA GEMM, K-split x2, one-chunk-deep register pipeline ----
__global__ __launch_bounds__(128) void moe_gate_mfma_kernel(
    const float* __restrict__ x, const unsigned short* __restrict__ wf,
    float* __restrict__ out, int ntok, unsigned char* __restrict__ flags)
{
    __shared__ float red[64][17];                 // wave1 partials, conflict-free stride
    __shared__ __align__(16) float ls[16][68];    // transposed logits

    const int tid  = threadIdx.x;
    const int wave = tid >> 6;                    // 0,1 = K-half
    const int lane = tid & 63;
    const int t0   = blockIdx.x * 16;
    const int l15  = lane & 15;
    const int lg   = lane >> 4;

    const float* xp = x + (size_t)(t0 + l15) * DIM + lg * 8 + wave * 1024;
    const unsigned short* wl = wf + (size_t)wave * 16 * 8192 + lane * 8;

    f32x4 acc0 = {0.f,0.f,0.f,0.f}, acc1 = {0.f,0.f,0.f,0.f};
    f32x4 acc2 = {0.f,0.f,0.f,0.f}, acc3 = {0.f,0.f,0.f,0.f};

    // ---- prologue: chunk 0 in flight ----
    float4 pa0 = *(const float4*)(xp);
    float4 pa1 = *(const float4*)(xp + 4);
    float4 pa2 = *(const float4*)(xp + 32);
    float4 pa3 = *(const float4*)(xp + 36);

    bf16x8 b0h, b0l, b1h, b1l, b2h, b2l, b3h, b3l;
    bf16x8 b4h, b4l, b5h, b5l, b6h, b6l, b7h, b7l;
    {
        const unsigned short* w0 = wl;
        b0h = *(const bf16x8*)(w0 + 0);    b0l = *(const bf16x8*)(w0 + 512);
        b1h = *(const bf16x8*)(w0 + 1024); b1l = *(const bf16x8*)(w0 + 1536);
        b2h = *(const bf16x8*)(w0 + 2048); b2l = *(const bf16x8*)(w0 + 2560);
        b3h = *(const bf16x8*)(w0 + 3072); b3l = *(const bf16x8*)(w0 + 3584);
        b4h = *(const bf16x8*)(w0 + 4096); b4l = *(const bf16x8*)(w0 + 4608);
        b5h = *(const bf16x8*)(w0 + 5120); b5l = *(const bf16x8*)(w0 + 5632);
        b6h = *(const bf16x8*)(w0 + 6144); b6l = *(const bf16x8*)(w0 + 6656);
        b7h = *(const bf16x8*)(w0 + 7168); b7l = *(const bf16x8*)(w0 + 7680);
    }

#pragma unroll
    for (int c = 0; c < 16; ++c) {
        // ---- issue chunk c+1 loads (B first: longest distance to use) ----
        bf16x8 n0h = b0h, n0l = b0l, n1h = b1h, n1l = b1l;
        bf16x8 n2h = b2h, n2l = b2l, n3h = b3h, n3l = b3l;
        bf16x8 n4h = b4h, n4l = b4l, n5h = b5h, n5l = b5l;
        bf16x8 n6h = b6h, n6l = b6l, n7h = b7h, n7l = b7l;
        float4 pb0 = pa0, pb1 = pa1, pb2 = pa2, pb3 = pa3;
        if (c < 15) {
            const unsigned short* wn = wl + (size_t)(c + 1) * 8192;
            n0h = *(const bf16x8*)(wn + 0);    n0l = *(const bf16x8*)(wn + 512);
            n1h = *(const bf16x8*)(wn + 1024); n1l = *(const bf16x8*)(wn + 1536);
            n2h = *(const bf16x8*)(wn + 2048); n2l = *(const bf16x8*)(wn + 2560);
            n3h = *(const bf16x8*)(wn + 3072); n3l = *(const bf16x8*)(wn + 3584);
            n4h = *(const bf16x8*)(wn + 4096); n4l = *(const bf16x8*)(wn + 4608);
            n5h = *(const bf16x8*)(wn + 5120); n5l = *(const bf16x8*)(wn + 5632);
            n6h = *(const bf16x8*)(wn + 6144); n6l = *(const bf16x8*)(wn + 6656);
            n7h = *(const bf16x8*)(wn + 7168); n7l = *(const bf16x8*)(wn + 7680);
            const float* xn = xp + (c + 1) * 64;
            pb0 = *(const float4*)(xn);
            pb1 = *(const float4*)(xn + 4);
            pb2 = *(const float4*)(xn + 32);
            pb3 = *(const float4*)(xn + 36);
        }

        // ---- split current x (VALU, covers load latency) ----
        bf16x8 Ah0, Al0, Ah1, Al1;
        SPLS(pa0.x, Ah0, Al0, 0) SPLS(pa0.y, Ah0, Al0, 1) SPLS(pa0.z, Ah0, Al0, 2) SPLS(pa0.w, Ah0, Al0, 3)
        SPLS(pa1.x, Ah0, Al0, 4) SPLS(pa1.y, Ah0, Al0, 5) SPLS(pa1.z, Ah0, Al0, 6) SPLS(pa1.w, Ah0, Al0, 7)
        SPLS(pa2.x, Ah1, Al1, 0) SPLS(pa2.y, Ah1, Al1, 1) SPLS(pa2.z, Ah1, Al1, 2) SPLS(pa2.w, Ah1, Al1, 3)
        SPLS(pa3.x, Ah1, Al1, 4) SPLS(pa3.y, Ah1, Al1, 5) SPLS(pa3.z, Ah1, Al1, 6) SPLS(pa3.w, Ah1, Al1, 7)

        // ---- MFMAs on current B (loaded one full chunk ago), round-robin over acc ----
        // ks = 0
        acc0 = __builtin_amdgcn_mfma_f32_16x16x32_bf16(Ah0, b0h, acc0, 0, 0, 0);
        acc1 = __builtin_amdgcn_mfma_f32_16x16x32_bf16(Ah0, b1h, acc1, 0, 0, 0);
        acc2 = __builtin_amdgcn_mfma_f32_16x16x32_bf16(Ah0, b2h, acc2, 0, 0, 0);
        acc3 = __builtin_amdgcn_mfma_f32_16x16x32_bf16(Ah0, b3h, acc3, 0, 0, 0);
        acc0 = __builtin_amdgcn_mfma_f32_16x16x32_bf16(Ah0, b0l, acc0, 0, 0, 0);
        acc1 = __builtin_amdgcn_mfma_f32_16x16x32_bf16(Ah0, b1l, acc1, 0, 0, 0);
        acc2 = __builtin_amdgcn_mfma_f32_16x16x32_bf16(Ah0, b2l, acc2, 0, 0, 0);
        acc3 = __builtin_amdgcn_mfma_f32_16x16x32_bf16(Ah0, b3l, acc3, 0, 0, 0);
        acc0 = __builtin_amdgcn_mfma_f32_16x16x32_bf16(Al0, b0h, acc0, 0, 0, 0);
        acc1 = __builtin_amdgcn_mfma_f32_16x16x32_bf16(Al0, b1h, acc1, 0, 0, 0);
        acc2 = __builtin_amdgcn_mfma_f32_16x16x32_bf16(Al0, b2h, acc2, 0, 0, 0);
        acc3 = __builtin_amdgcn_mfma_f32_16x16x32_bf16(Al0, b3h, acc3, 0, 0, 0);
        // ks = 1
        acc0 = __builtin_amdgcn_mfma_f32_16x16x32_bf16(Ah1, b4h, acc0, 0, 0, 0);
        acc1 = __builtin_amdgcn_mfma_f32_16x16x32_bf16(Ah1, b5h, acc1, 0, 0, 0);
        acc2 = __builtin_amdgcn_mfma_f32_16x16x32_bf16(Ah1, b6h, acc2, 0, 0, 0);
        acc3 = __builtin_amdgcn_mfma_f32_16x16x32_bf16(Ah1, b7h, acc3, 0, 0, 0);
        acc0 = __builtin_amdgcn_mfma_f32_16x16x32_bf16(Ah1, b4l, acc0, 0, 0, 0);
        acc1 = __builtin_amdgcn_mfma_f32_16x16x32_bf16(Ah1, b5l, acc1, 0, 0, 0);
        acc2 = __builtin_amdgcn_mfma_f32_16x16x32_bf16(Ah1, b6l, acc2, 0, 0, 0);
        acc3 = __builtin_amdgcn_mfma_f32_16x16x32_bf16(Ah1, b7l, acc3, 0, 0, 0);
        acc0 = __builtin_amdgcn_mfma_f32_16x16x32_bf16(Al1, b4h, acc0, 0, 0, 0);
        acc1 = __builtin_amdgcn_mfma_f32_16x16x32_bf16(Al1, b5h, acc1, 0, 0, 0);
        acc2 = __builtin_amdgcn_mfma_f32_16x16x32_bf16(Al1, b6h, acc2, 0, 0, 0);
        acc3 = __builtin_amdgcn_mfma_f32_16x16x32_bf16(Al1, b7h, acc3, 0, 0, 0);

        // ---- rotate pipeline (renamed away by full unroll) ----
        b0h = n0h; b0l = n0l; b1h = n1h; b1l = n1l;
        b2h = n2h; b2l = n2l; b3h = n3h; b3l = n3l;
        b4h = n4h; b4l = n4l; b5h = n5h; b5l = n5l;
        b6h = n6h; b6l = n6l; b7h = n7h; b7l = n7l;
        pa0 = pb0; pa1 = pb1; pa2 = pb2; pa3 = pb3;
    }

    // ---- cross-wave K reduction via LDS ----
    if (wave == 1) {
#pragma unroll
        for (int i = 0; i < 4; ++i) {
            red[lane][ 0 + i] = acc0[i];
            red[lane][ 4 + i] = acc1[i];
            red[lane][ 8 + i] = acc2[i];
            red[lane][12 + i] = acc3[i];
        }
    }
    __syncthreads();
    if (wave == 0) {
#pragma unroll
        for (int i = 0; i < 4; ++i) {
            acc0[i] += red[lane][ 0 + i];
            acc1[i] += red[lane][ 4 + i];
            acc2[i] += red[lane][ 8 + i];
            acc3[i] += red[lane][12 + i];
        }
        const int rb = lg * 4;
        ls[rb + 0][ 0 + l15] = acc0[0]; ls[rb + 1][ 0 + l15] = acc0[1];
        ls[rb + 2][ 0 + l15] = acc0[2]; ls[rb + 3][ 0 + l15] = acc0[3];
        ls[rb + 0][16 + l15] = acc1[0]; ls[rb + 1][16 + l15] = acc1[1];
        ls[rb + 2][16 + l15] = acc1[2]; ls[rb + 3][16 + l15] = acc1[3];
        ls[rb + 0][32 + l15] = acc2[0]; ls[rb + 1][32 + l15] = acc2[1];
        ls[rb + 2][32 + l15] = acc2[2]; ls[rb + 3][32 + l15] = acc2[3];
        ls[rb + 0][48 + l15] = acc3[0]; ls[rb + 1][48 + l15] = acc3[1];
        ls[rb + 2][48 + l15] = acc3[2]; ls[rb + 3][48 + l15] = acc3[3];
    }
    __syncthreads();

    if (wave == 0) {
        // ---- softmax + top-8: 4 lanes per token, 16 experts each (R6-R10 construct) ----
        const int tok = l15;
        const int sub = lg;

        float r[16];
#pragma unroll
        for (int k = 0; k < 4; ++k) {
            float4 v = *(const float4*)(&ls[tok][sub * 16 + 4 * k]);
            r[4 * k] = v.x; r[4 * k + 1] = v.y; r[4 * k + 2] = v.z; r[4 * k + 3] = v.w;
        }

        float m = r[0];
#pragma unroll
        for (int i = 1; i < 16; ++i) m = fmaxf(m, r[i]);
        m = fmaxf(m, __shfl_xor(m, 16));
        m = fmaxf(m, __shfl_xor(m, 32));

        float ex[16]; float s = 0.f;
#pragma unroll
        for (int i = 0; i < 16; ++i) { ex[i] = expf(r[i] - m); s += ex[i]; }
        s += __shfl_xor(s, 16);
        s += __shfl_xor(s, 32);

        float pr[16];
#pragma unroll
        for (int i = 0; i < 16; ++i) pr[i] = ex[i] / s;

        uint64_t prev = ~0ull;
        float ovals[8]; float oidx[8];
        float prevp = 0.f; int nearf = 0;
#pragma unroll
        for (int p = 0; p < 8; ++p) {
            uint64_t best = 0;
#pragma unroll
            for (int i = 0; i < 16; ++i) {
                uint64_t key = ((uint64_t)__float_as_uint(pr[i]) << 32)
                             | (uint64_t)(63 - (sub * 16 + i));
                if (key < prev && key > best) best = key;
            }
            {
                uint32_t bh = (uint32_t)(best >> 32), bl = (uint32_t)best;
                uint32_t oh = __shfl_xor(bh, 16), ol = __shfl_xor(bl, 16);
                uint64_t ob = ((uint64_t)oh << 32) | ol;
                if (ob > best) best = ob;
                bh = (uint32_t)(best >> 32); bl = (uint32_t)best;
                oh = __shfl_xor(bh, 32); ol = __shfl_xor(bl, 32);
                ob = ((uint64_t)oh << 32) | ol;
                if (ob > best) best = ob;
            }
            prev = best;
            float pv = __uint_as_float((uint32_t)(best >> 32));
            if (p > 0 && (prevp - pv) < TAU * pv) nearf = 1;
            prevp = pv;
            ovals[p] = pv;
            oidx[p]  = (float)(63 - (int)(best & 63));
        }
        {
            uint64_t best = 0;
#pragma unroll
            for (int i = 0; i < 16; ++i) {
                uint64_t key = ((uint64_t)__float_as_uint(pr[i]) << 32)
                             | (uint64_t)(63 - (sub * 16 + i));
                if (key < prev && key > best) best = key;
            }
            {
                uint32_t bh = (uint32_t)(best >> 32), bl = (uint32_t)best;
                uint32_t oh = __shfl_xor(bh, 16), ol = __shfl_xor(bl, 16);
                uint64_t ob = ((uint64_t)oh << 32) | ol;
                if (ob > best) best = ob;
                bh = (uint32_t)(best >> 32); bl = (uint32_t)best;
                oh = __shfl_xor(bh, 32); ol = __shfl_xor(bl, 32);
                ob = ((uint64_t)oh << 32) | ol;
                if (ob > best) best = ob;
            }
            float pv9 = __uint_as_float((uint32_t)(best >> 32));
            if ((prevp - pv9) < TAU * pv9) nearf = 1;
        }

        if (sub == 0) {
            size_t gtok = (size_t)(t0 + tok);
            float* vo = out + gtok * 8;
            float* io = out + (size_t)ntok * 8 + gtok * 8;
            *(float4*)(vo)     = make_float4(ovals[0], ovals[1], ovals[2], ovals[3]);
            *(float4*)(vo + 4) = make_float4(ovals[4], ovals[5], ovals[6], ovals[7]);
            *(float4*)(io)     = make_float4(oidx[0], oidx[1], oidx[2], oidx[3]);
            *(float4*)(io + 4) = make_float4(oidx[4], oidx[5], oidx[6], oidx[7]);
            flags[gtok] = (unsigned char)nearf;
        }
    }
}

// ------- Pass 2: f64 refinement, 1 wave/token, no LDS, no barriers (R10 verbatim) -------
__global__ __launch_bounds__(64) void moe_gate_refine_kernel(
    const float* __restrict__ x, const float* __restrict__ wgt,
    float* __restrict__ out, int ntok, const unsigned char* __restrict__ flags)
{
    const int lane = threadIdx.x;        // expert id 0..63
    const int base = blockIdx.x * 4;

    for (int t = 0; t < 4; ++t) {
        const int tok = base + t;
        if (flags[tok] == 0) continue;   // wave-uniform

        const float* xp = x   + (size_t)tok  * DIM;
        const float* wp = wgt + (size_t)lane * DIM;
        double a0 = 0.0, a1 = 0.0, a2 = 0.0, a3 = 0.0;
        for (int k = 0; k < DIM; k += 16) {
            float4 xv0 = *(const float4*)(xp + k);
            float4 wv0 = *(const float4*)(wp + k);
            float4 xv1 = *(const float4*)(xp + k + 4);
            float4 wv1 = *(const float4*)(wp + k + 4);
            float4 xv2 = *(const float4*)(xp + k + 8);
            float4 wv2 = *(const float4*)(wp + k + 8);
            float4 xv3 = *(const float4*)(xp + k + 12);
            float4 wv3 = *(const float4*)(wp + k + 12);
            a0 = fma((double)xv0.x, (double)wv0.x, a0);
            a0 = fma((double)xv0.y, (double)wv0.y, a0);
            a0 = fma((double)xv0.z, (double)wv0.z, a0);
            a0 = fma((double)xv0.w, (double)wv0.w, a0);
            a1 = fma((double)xv1.x, (double)wv1.x, a1);
            a1 = fma((double)xv1.y, (double)wv1.y, a1);
            a1 = fma((double)xv1.z, (double)wv1.z, a1);
            a1 = fma((double)xv1.w, (double)wv1.w, a1);
            a2 = fma((double)xv2.x, (double)wv2.x, a2);
            a2 = fma((double)xv2.y, (double)wv2.y, a2);
            a2 = fma((double)xv2.z, (double)wv2.z, a2);
            a2 = fma((double)xv2.w, (double)wv2.w, a2);
            a3 = fma((double)xv3.x, (double)wv3.x, a3);
            a3 = fma((double)xv3.y, (double)wv3.y, a3);
            a3 = fma((double)xv3.z, (double)wv3.z, a3);
            a3 = fma((double)xv3.w, (double)wv3.w, a3);
        }
        double acc = (a0 + a1) + (a2 + a3);

        uint64_t mykey = (mono64(acc) & ~63ull) | (uint64_t)(63 - lane);

        uint64_t mk = mykey;
        {
            unsigned long long o;
            o = __shfl_xor((unsigned long long)mk, 1);  if ((uint64_t)o > mk) mk = (uint64_t)o;
            o = __shfl_xor((unsigned long long)mk, 2);  if ((uint64_t)o > mk) mk = (uint64_t)o;
            o = __shfl_xor((unsigned long long)mk, 4);  if ((uint64_t)o > mk) mk = (uint64_t)o;
            o = __shfl_xor((unsigned long long)mk, 8);  if ((uint64_t)o > mk) mk = (uint64_t)o;
            o = __shfl_xor((unsigned long long)mk, 16); if ((uint64_t)o > mk) mk = (uint64_t)o;
            o = __shfl_xor((unsigned long long)mk, 32); if ((uint64_t)o > mk) mk = (uint64_t)o;
        }
        double md = unmono64(mk & ~63ull);

        float s = expf((float)(acc - md));
        s += __shfl_xor(s, 1);
        s += __shfl_xor(s, 2);
        s += __shfl_xor(s, 4);
        s += __shfl_xor(s, 8);
        s += __shfl_xor(s, 16);
        s += __shfl_xor(s, 32);

        float* vo = out + (size_t)tok * 8;
        float* io = out + (size_t)ntok * 8 + (size_t)tok * 8;

        uint64_t prev = ~0ull;
        for (int q = 0; q < 8; ++q) {
            uint64_t best = (mykey < prev) ? mykey : 0;
            {
                unsigned long long o;
                o = __shfl_xor((unsigned long long)best, 1);  if ((uint64_t)o > best) best = (uint64_t)o;
                o = __shfl_xor((unsigned long long)best, 2);  if ((uint64_t)o > best) best = (uint64_t)o;
                o = __shfl_xor((unsigned long long)best, 4);  if ((uint64_t)o > best) best = (uint64_t)o;
                o = __shfl_xor((unsigned long long)best, 8);  if ((uint64_t)o > best) best = (uint64_t)o;
                o = __shfl_xor((unsigned long long)best, 16); if ((uint64_t)o > best) best = (uint64_t)o;
                o = __shfl_xor((unsigned long long)best, 32); if ((uint64_t)o > best) best = (uint64_t)o;
            }
            prev = best;
            if (lane == 0) {
                vo[q] = expf((float)(unmono64(best & ~63ull) - md)) / s;
                io[q] = (float)(63 - (int)(best & 63ull));
            }
        }
    }
}

extern "C" void kernel_launch(void* const* d_in, const int* in_sizes, int n_in,
                              void* d_out, int out_size, void* d_ws, size_t ws_size,
                              hipStream_t stream) {
    const float* x   = (const float*)d_in[0];
    const float* wgt = (const float*)d_in[1];
    float* out = (float*)d_out;
    const int ntok = in_sizes[0] / DIM;   // 32768

    unsigned short* wf    = (unsigned short*)d_ws;                   // 512 KB
    unsigned char*  flags = (unsigned char*)d_ws + FLAGS_OFF;        // ntok bytes

    hipLaunchKernelGGL(wsplit_kernel, dim3(64), dim3(256), 0, stream, wgt, wf);
    hipLaunchKernelGGL(moe_gate_mfma_kernel, dim3(ntok / 16), dim3(128), 0, stream,
                       x, wf, out, ntok, flags);
    hipLaunchKernelGGL(moe_gate_refine_kernel, dim3(ntok / 4), dim3(64), 0, stream,
                       x, wgt, out, ntok, flags);
}

// Round 12
// 181.613 us; speedup vs baseline: 1.2071x; 1.0596x over previous
//
#include <hip/hip_runtime.h>
#include <stdint.h>

#define DIM     2048
#define NEXP    64
#define NCHUNK  32        // K chunks of 64
#define TPB     64        // tokens per block (pass 1)
#define TAU     2e-4f     // near-tie threshold on relative prob gaps

#define WFRAG_USHORTS (NCHUNK * 8192)        // 512 KB fragment image
#define FLAGS_OFF     (WFRAG_USHORTS * 2)    // byte offset of flags in d_ws

typedef __attribute__((ext_vector_type(8))) short bf16x8;
typedef __attribute__((ext_vector_type(8))) unsigned short u16x8;
typedef __attribute__((ext_vector_type(4))) float f32x4;

__device__ inline unsigned short bf16_rne(float f) {
    uint32_t u = __float_as_uint(f);
    return (unsigned short)((u + 0x7FFFu + ((u >> 16) & 1u)) >> 16);
}
__device__ inline float bf16_to_f(unsigned short h) {
    return __uint_as_float(((uint32_t)h) << 16);
}
__device__ inline uint64_t mono64(double d) {
    uint64_t u = (uint64_t)__double_as_longlong(d);
    return (u >> 63) ? ~u : (u | 0x8000000000000000ull);
}
__device__ inline double unmono64(uint64_t m) {
    uint64_t b = (m >> 63) ? (m & 0x7fffffffffffffffull) : ~m;
    return __longlong_as_double((long long)b);
}

#define SPL(F, HV, LV, J)  { unsigned short _h = bf16_rne(F); HV[J] = _h; LV[J] = bf16_rne((F) - bf16_to_f(_h)); }
#define SPLS(F, HV, LV, J) { unsigned short _h = bf16_rne(F); HV[J] = (short)_h; LV[J] = (short)bf16_rne((F) - bf16_to_f(_h)); }

__device__ __forceinline__ void g2l16(const void* g, void* l) {
    __builtin_amdgcn_global_load_lds(
        (__attribute__((address_space(1))) void*)(g),
        (__attribute__((address_space(3))) void*)(l),
        16, 0, 0);
}

// ---- Kernel 0: split w into bf16 hi/lo B-fragment image ----
// layout (ushort): [c:32][ks:2][t:4][plane:2][lane:64][j:8]  (16 KB per chunk, contiguous)
__global__ __launch_bounds__(256) void wsplit_kernel(
    const float* __restrict__ wgt, unsigned short* __restrict__ wf)
{
    int g = blockIdx.x * 256 + threadIdx.x;   // 0..16383 = c*512 + s*256 + t*64 + l
    int l = g & 63;
    int t = (g >> 6) & 3;
    int s = (g >> 8) & 1;
    int c = g >> 9;
    int e = (l & 15) + 16 * t;
    int k = c * 64 + s * 32 + ((l >> 4) * 8);
    const float* wp = wgt + (size_t)e * DIM + k;
    float4 f0 = *(const float4*)(wp);
    float4 f1 = *(const float4*)(wp + 4);
    u16x8 h, lo;
    SPL(f0.x, h, lo, 0) SPL(f0.y, h, lo, 1) SPL(f0.z, h, lo, 2) SPL(f0.w, h, lo, 3)
    SPL(f1.x, h, lo, 4) SPL(f1.y, h, lo, 5) SPL(f1.z, h, lo, 6) SPL(f1.w, h, lo, 7)
    size_t base = ((((size_t)(c * 2 + s) * 4 + t) * 2 + 0) * 64 + l) * 8;
    *(u16x8*)(wf + base)       = h;
    *(u16x8*)(wf + base + 512) = lo;   // plane stride = 64*8
}

// stage chunk CC: x tile (swizzled source -> linear LDS) + B tile (linear)
#define STAGE_CHUNK(CC, XD, BD)                                                   \
    {                                                                             \
        _Pragma("unroll")                                                         \
        for (int s_ = 0; s_ < 4; ++s_) {                                          \
            int idx_ = wave * 256 + s_ * 64 + lane;                               \
            int row_ = idx_ >> 4;                                                 \
            int p_   = idx_ & 15;                                                 \
            int g_   = p_ ^ (row_ & 7);                                           \
            const unsigned char* gsrc_ = (const unsigned char*)x +                \
                (((size_t)(t0 + row_) * DIM + (CC) * 64 + g_ * 4) << 2);          \
            g2l16(gsrc_, (XD) + wave * 4096 + s_ * 1024);                         \
        }                                                                         \
        const unsigned char* wfb_ = (const unsigned char*)wf + (size_t)(CC) * 16384; \
        _Pragma("unroll")                                                         \
        for (int s_ = 0; s_ < 4; ++s_) {                                          \
            g2l16(wfb_ + wave * 4096 + s_ * 1024 + lane * 16,                     \
                  (BD) + wave * 4096 + s_ * 1024);                                \
        }                                                                         \
    }

// ---- Pass 1: bf16x3 MFMA GEMM, global_load_lds double-buffered staging ----
__global__ __launch_bounds__(256) void moe_gate_mfma_kernel(
    const float* __restrict__ x, const unsigned short* __restrict__ wf,
    float* __restrict__ out, int ntok, unsigned char* __restrict__ flags)
{
    __shared__ __align__(16) unsigned char smem[65536];   // x0|x1|b0|b1, 16 KB each

    const int tid  = threadIdx.x;
    const int wave = tid >> 6;
    const int lane = tid & 63;
    const int t0   = blockIdx.x * TPB;
    const int l15  = lane & 15;
    const int lg   = lane >> 4;

    unsigned char* const xb0 = smem;
    unsigned char* const xb1 = smem + 16384;
    unsigned char* const bb0 = smem + 32768;
    unsigned char* const bb1 = smem + 49152;

    f32x4 acc0 = {0.f,0.f,0.f,0.f}, acc1 = {0.f,0.f,0.f,0.f};
    f32x4 acc2 = {0.f,0.f,0.f,0.f}, acc3 = {0.f,0.f,0.f,0.f};

    STAGE_CHUNK(0, xb0, bb0);

    const int s7 = l15 & 7;
    for (int c = 0; c < NCHUNK; ++c) {
        __syncthreads();   // drains vmcnt: buf[c&1] staged; compute(c-1) finished
        unsigned char* xcur = (c & 1) ? xb1 : xb0;
        unsigned char* bcur = (c & 1) ? bb1 : bb0;
        if (c + 1 < NCHUNK) {
            unsigned char* xnxt = (c & 1) ? xb0 : xb1;
            unsigned char* bnxt = (c & 1) ? bb0 : bb1;
            STAGE_CHUNK(c + 1, xnxt, bnxt);
        }

        // ---- A fragments from swizzled x tile ----
        const unsigned char* xrow = xcur + (wave * 16 + l15) * 256;
        float4 fa0 = *(const float4*)(xrow + (((2 * lg)     ^ s7) * 16));
        float4 fa1 = *(const float4*)(xrow + (((2 * lg + 1) ^ s7) * 16));
        float4 fa2 = *(const float4*)(xrow + (((8 + 2 * lg) ^ s7) * 16));
        float4 fa3 = *(const float4*)(xrow + (((9 + 2 * lg) ^ s7) * 16));

        bf16x8 Ah0, Al0, Ah1, Al1;
        SPLS(fa0.x, Ah0, Al0, 0) SPLS(fa0.y, Ah0, Al0, 1) SPLS(fa0.z, Ah0, Al0, 2) SPLS(fa0.w, Ah0, Al0, 3)
        SPLS(fa1.x, Ah0, Al0, 4) SPLS(fa1.y, Ah0, Al0, 5) SPLS(fa1.z, Ah0, Al0, 6) SPLS(fa1.w, Ah0, Al0, 7)
        SPLS(fa2.x, Ah1, Al1, 0) SPLS(fa2.y, Ah1, Al1, 1) SPLS(fa2.z, Ah1, Al1, 2) SPLS(fa2.w, Ah1, Al1, 3)
        SPLS(fa3.x, Ah1, Al1, 4) SPLS(fa3.y, Ah1, Al1, 5) SPLS(fa3.z, Ah1, Al1, 6) SPLS(fa3.w, Ah1, Al1, 7)

        // ---- B fragments from LDS (shared by all 4 waves), 6 MFMAs per tile ----
        const unsigned short* bu = (const unsigned short*)bcur;
        {
            bf16x8 Bh0 = *(const bf16x8*)(bu +        0 + lane * 8);
            bf16x8 Bl0 = *(const bf16x8*)(bu +      512 + lane * 8);
            bf16x8 Bh1 = *(const bf16x8*)(bu + 4096 + 0 + lane * 8);
            bf16x8 Bl1 = *(const bf16x8*)(bu + 4096 + 512 + lane * 8);
            acc0 = __builtin_amdgcn_mfma_f32_16x16x32_bf16(Ah0, Bh0, acc0, 0, 0, 0);
            acc0 = __builtin_amdgcn_mfma_f32_16x16x32_bf16(Ah0, Bl0, acc0, 0, 0, 0);
            acc0 = __builtin_amdgcn_mfma_f32_16x16x32_bf16(Al0, Bh0, acc0, 0, 0, 0);
            acc0 = __builtin_amdgcn_mfma_f32_16x16x32_bf16(Ah1, Bh1, acc0, 0, 0, 0);
            acc0 = __builtin_amdgcn_mfma_f32_16x16x32_bf16(Ah1, Bl1, acc0, 0, 0, 0);
            acc0 = __builtin_amdgcn_mfma_f32_16x16x32_bf16(Al1, Bh1, acc0, 0, 0, 0);
        }
        {
            bf16x8 Bh0 = *(const bf16x8*)(bu + 1024 + lane * 8);
            bf16x8 Bl0 = *(const bf16x8*)(bu + 1536 + lane * 8);
            bf16x8 Bh1 = *(const bf16x8*)(bu + 5120 + lane * 8);
            bf16x8 Bl1 = *(const bf16x8*)(bu + 5632 + lane * 8);
            acc1 = __builtin_amdgcn_mfma_f32_16x16x32_bf16(Ah0, Bh0, acc1, 0, 0, 0);
            acc1 = __builtin_amdgcn_mfma_f32_16x16x32_bf16(Ah0, Bl0, acc1, 0, 0, 0);
            acc1 = __builtin_amdgcn_mfma_f32_16x16x32_bf16(Al0, Bh0, acc1, 0, 0, 0);
            acc1 = __builtin_amdgcn_mfma_f32_16x16x32_bf16(Ah1, Bh1, acc1, 0, 0, 0);
            acc1 = __builtin_amdgcn_mfma_f32_16x16x32_bf16(Ah1, Bl1, acc1, 0, 0, 0);
            acc1 = __builtin_amdgcn_mfma_f32_16x16x32_bf16(Al1, Bh1, acc1, 0, 0, 0);
        }
        {
            bf16x8 Bh0 = *(const bf16x8*)(bu + 2048 + lane * 8);
            bf16x8 Bl0 = *(const bf16x8*)(bu + 2560 + lane * 8);
            bf16x8 Bh1 = *(const bf16x8*)(bu + 6144 + lane * 8);
            bf16x8 Bl1 = *(const bf16x8*)(bu + 6656 + lane * 8);
            acc2 = __builtin_amdgcn_mfma_f32_16x16x32_bf16(Ah0, Bh0, acc2, 0, 0, 0);
            acc2 = __builtin_amdgcn_mfma_f32_16x16x32_bf16(Ah0, Bl0, acc2, 0, 0, 0);
            acc2 = __builtin_amdgcn_mfma_f32_16x16x32_bf16(Al0, Bh0, acc2, 0, 0, 0);
            acc2 = __builtin_amdgcn_mfma_f32_16x16x32_bf16(Ah1, Bh1, acc2, 0, 0, 0);
            acc2 = __builtin_amdgcn_mfma_f32_16x16x32_bf16(Ah1, Bl1, acc2, 0, 0, 0);
            acc2 = __builtin_amdgcn_mfma_f32_16x16x32_bf16(Al1, Bh1, acc2, 0, 0, 0);
        }
        {
            bf16x8 Bh0 = *(const bf16x8*)(bu + 3072 + lane * 8);
            bf16x8 Bl0 = *(const bf16x8*)(bu + 3584 + lane * 8);
            bf16x8 Bh1 = *(const bf16x8*)(bu + 7168 + lane * 8);
            bf16x8 Bl1 = *(const bf16x8*)(bu + 7680 + lane * 8);
            acc3 = __builtin_amdgcn_mfma_f32_16x16x32_bf16(Ah0, Bh0, acc3, 0, 0, 0);
            acc3 = __builtin_amdgcn_mfma_f32_16x16x32_bf16(Ah0, Bl0, acc3, 0, 0, 0);
            acc3 = __builtin_amdgcn_mfma_f32_16x16x32_bf16(Al0, Bh0, acc3, 0, 0, 0);
            acc3 = __builtin_amdgcn_mfma_f32_16x16x32_bf16(Ah1, Bh1, acc3, 0, 0, 0);
            acc3 = __builtin_amdgcn_mfma_f32_16x16x32_bf16(Ah1, Bl1, acc3, 0, 0, 0);
            acc3 = __builtin_amdgcn_mfma_f32_16x16x32_bf16(Al1, Bh1, acc3, 0, 0, 0);
        }
    }

    // ---- epilogue: transpose logits via LDS (reuse staging area), per wave ----
    __syncthreads();
    float* lsw = (float*)smem + wave * 1088;   // 16*68 floats per wave
    {
        const int rb = lg * 4;
        lsw[(rb + 0) * 68 +  0 + l15] = acc0[0]; lsw[(rb + 1) * 68 +  0 + l15] = acc0[1];
        lsw[(rb + 2) * 68 +  0 + l15] = acc0[2]; lsw[(rb + 3) * 68 +  0 + l15] = acc0[3];
        lsw[(rb + 0) * 68 + 16 + l15] = acc1[0]; lsw[(rb + 1) * 68 + 16 + l15] = acc1[1];
        lsw[(rb + 2) * 68 + 16 + l15] = acc1[2]; lsw[(rb + 3) * 68 + 16 + l15] = acc1[3];
        lsw[(rb + 0) * 68 + 32 + l15] = acc2[0]; lsw[(rb + 1) * 68 + 32 + l15] = acc2[1];
        lsw[(rb + 2) * 68 + 32 + l15] = acc2[2]; lsw[(rb + 3) * 68 + 32 + l15] = acc2[3];
        lsw[(rb + 0) * 68 + 48 + l15] = acc3[0]; lsw[(rb + 1) * 68 + 48 + l15] = acc3[1];
        lsw[(rb + 2) * 68 + 48 + l15] = acc3[2]; lsw[(rb + 3) * 68 + 48 + l15] = acc3[3];
    }
    __syncthreads();

    // ---- softmax + top-8: 4 lanes per token, 16 experts each (R6-R11 construct) ----
    const int tok = l15;
    const int sub = lg;

    float r[16];
#pragma unroll
    for (int k = 0; k < 4; ++k) {
        float4 v = *(const float4*)(&lsw[tok * 68 + sub * 16 + 4 * k]);
        r[4 * k] = v.x; r[4 * k + 1] = v.y; r[4 * k + 2] = v.z; r[4 * k + 3] = v.w;
    }

    float m = r[0];
#pragma unroll
    for (int i = 1; i < 16; ++i) m = fmaxf(m, r[i]);
    m = fmaxf(m, __shfl_xor(m, 16));
    m = fmaxf(m, __shfl_xor(m, 32));

    float ex[16]; float s = 0.f;
#pragma unroll
    for (int i = 0; i < 16; ++i) { ex[i] = expf(r[i] - m); s += ex[i]; }
    s += __shfl_xor(s, 16);
    s += __shfl_xor(s, 32);

    float pr[16];
#pragma unroll
    for (int i = 0; i < 16; ++i) pr[i] = ex[i] / s;

    uint64_t prev = ~0ull;
    float ovals[8]; float oidx[8];
    float prevp = 0.f; int nearf = 0;
#pragma unroll
    for (int p = 0; p < 8; ++p) {
        uint64_t best = 0;
#pragma unroll
        for (int i = 0; i < 16; ++i) {
            uint64_t key = ((uint64_t)__float_as_uint(pr[i]) << 32)
                         | (uint64_t)(63 - (sub * 16 + i));
            if (key < prev && key > best) best = key;
        }
        {
            uint32_t bh = (uint32_t)(best >> 32), bl = (uint32_t)best;
            uint32_t oh = __shfl_xor(bh, 16), ol = __shfl_xor(bl, 16);
            uint64_t ob = ((uint64_t)oh << 32) | ol;
            if (ob > best) best = ob;
            bh = (uint32_t)(best >> 32); bl = (uint32_t)best;
            oh = __shfl_xor(bh, 32); ol = __shfl_xor(bl, 32);
            ob = ((uint64_t)oh << 32) | ol;
            if (ob > best) best = ob;
        }
        prev = best;
        float pv = __uint_as_float((uint32_t)(best >> 32));
        if (p > 0 && (prevp - pv) < TAU * pv) nearf = 1;
        prevp = pv;
        ovals[p] = pv;
        oidx[p]  = (float)(63 - (int)(best & 63));
    }
    {
        uint64_t best = 0;
#pragma unroll
        for (int i = 0; i < 16; ++i) {
            uint64_t key = ((uint64_t)__float_as_uint(pr[i]) << 32)
                         | (uint64_t)(63 - (sub * 16 + i));
            if (key < prev && key > best) best = key;
        }
        {
            uint32_t bh = (uint32_t)(best >> 32), bl = (uint32_t)best;
            uint32_t oh = __shfl_xor(bh, 16), ol = __shfl_xor(bl, 16);
            uint64_t ob = ((uint64_t)oh << 32) | ol;
            if (ob > best) best = ob;
            bh = (uint32_t)(best >> 32); bl = (uint32_t)best;
            oh = __shfl_xor(bh, 32); ol = __shfl_xor(bl, 32);
            ob = ((uint64_t)oh << 32) | ol;
            if (ob > best) best = ob;
        }
        float pv9 = __uint_as_float((uint32_t)(best >> 32));
        if ((prevp - pv9) < TAU * pv9) nearf = 1;
    }

    if (sub == 0) {
        size_t gtok = (size_t)(t0 + wave * 16 + tok);
        float* vo = out + gtok * 8;
        float* io = out + (size_t)ntok * 8 + gtok * 8;
        *(float4*)(vo)     = make_float4(ovals[0], ovals[1], ovals[2], ovals[3]);
        *(float4*)(vo + 4) = make_float4(ovals[4], ovals[5], ovals[6], ovals[7]);
        *(float4*)(io)     = make_float4(oidx[0], oidx[1], oidx[2], oidx[3]);
        *(float4*)(io + 4) = make_float4(oidx[4], oidx[5], oidx[6], oidx[7]);
        flags[gtok] = (unsigned char)nearf;
    }
}

// ------- Pass 2: f64 refinement, 1 wave/token, no LDS, no barriers (R11 verbatim) -------
__global__ __launch_bounds__(64) void moe_gate_refine_kernel(
    const float* __restrict__ x, const float* __restrict__ wgt,
    float* __restrict__ out, int ntok, const unsigned char* __restrict__ flags)
{
    const int lane = threadIdx.x;        // expert id 0..63
    const int base = blockIdx.x * 4;

    for (int t = 0; t < 4; ++t) {
        const int tok = base + t;
        if (flags[tok] == 0) continue;   // wave-uniform

        const float* xp = x   + (size_t)tok  * DIM;
        const float* wp = wgt + (size_t)lane * DIM;
        double a0 = 0.0, a1 = 0.0, a2 = 0.0, a3 = 0.0;
        for (int k = 0; k < DIM; k += 16) {
            float4 xv0 = *(const float4*)(xp + k);
            float4 wv0 = *(const float4*)(wp + k);
            float4 xv1 = *(const float4*)(xp + k + 4);
            float4 wv1 = *(const float4*)(wp + k + 4);
            float4 xv2 = *(const float4*)(xp + k + 8);
            float4 wv2 = *(const float4*)(wp + k + 8);
            float4 xv3 = *(const float4*)(xp + k + 12);
            float4 wv3 = *(const float4*)(wp + k + 12);
            a0 = fma((double)xv0.x, (double)wv0.x, a0);
            a0 = fma((double)xv0.y, (double)wv0.y, a0);
            a0 = fma((double)xv0.z, (double)wv0.z, a0);
            a0 = fma((double)xv0.w, (double)wv0.w, a0);
            a1 = fma((double)xv1.x, (double)wv1.x, a1);
            a1 = fma((double)xv1.y, (double)wv1.y, a1);
            a1 = fma((double)xv1.z, (double)wv1.z, a1);
            a1 = fma((double)xv1.w, (double)wv1.w, a1);
            a2 = fma((double)xv2.x, (double)wv2.x, a2);
            a2 = fma((double)xv2.y, (double)wv2.y, a2);
            a2 = fma((double)xv2.z, (double)wv2.z, a2);
            a2 = fma((double)xv2.w, (double)wv2.w, a2);
            a3 = fma((double)xv3.x, (double)wv3.x, a3);
            a3 = fma((double)xv3.y, (double)wv3.y, a3);
            a3 = fma((double)xv3.z, (double)wv3.z, a3);
            a3 = fma((double)xv3.w, (double)wv3.w, a3);
        }
        double acc = (a0 + a1) + (a2 + a3);

        uint64_t mykey = (mono64(acc) & ~63ull) | (uint64_t)(63 - lane);

        uint64_t mk = mykey;
        {
            unsigned long long o;
            o = __shfl_xor((unsigned long long)mk, 1);  if ((uint64_t)o > mk) mk = (uint64_t)o;
            o = __shfl_xor((unsigned long long)mk, 2);  if ((uint64_t)o > mk) mk = (uint64_t)o;
            o = __shfl_xor((unsigned long long)mk, 4);  if ((uint64_t)o > mk) mk = (uint64_t)o;
            o = __shfl_xor((unsigned long long)mk, 8);  if ((uint64_t)o > mk) mk = (uint64_t)o;
            o = __shfl_xor((unsigned long long)mk, 16); if ((uint64_t)o > mk) mk = (uint64_t)o;
            o = __shfl_xor((unsigned long long)mk, 32); if ((uint64_t)o > mk) mk = (uint64_t)o;
        }
        double md = unmono64(mk & ~63ull);

        float s = expf((float)(acc - md));
        s += __shfl_xor(s, 1);
        s += __shfl_xor(s, 2);
        s += __shfl_xor(s, 4);
        s += __shfl_xor(s, 8);
        s += __shfl_xor(s, 16);
        s += __shfl_xor(s, 32);

        float* vo = out + (size_t)tok * 8;
        float* io = out + (size_t)ntok * 8 + (size_t)tok * 8;

        uint64_t prev = ~0ull;
        for (int q = 0; q < 8; ++q) {
            uint64_t best = (mykey < prev) ? mykey : 0;
            {
                unsigned long long o;
                o = __shfl_xor((unsigned long long)best, 1);  if ((uint64_t)o > best) best = (uint64_t)o;
                o = __shfl_xor((unsigned long long)best, 2);  if ((uint64_t)o > best) best = (uint64_t)o;
                o = __shfl_xor((unsigned long long)best, 4);  if ((uint64_t)o > best) best = (uint64_t)o;
                o = __shfl_xor((unsigned long long)best, 8);  if ((uint64_t)o > best) best = (uint64_t)o;
                o = __shfl_xor((unsigned long long)best, 16); if ((uint64_t)o > best) best = (uint64_t)o;
                o = __shfl_xor((unsigned long long)best, 32); if ((uint64_t)o > best) best = (uint64_t)o;
            }
            prev = best;
            if (lane == 0) {
                vo[q] = expf((float)(unmono64(best & ~63ull) - md)) / s;
                io[q] = (float)(63 - (int)(best & 63ull));
            }
        }
    }
}

extern "C" void kernel_launch(void* const* d_in, const int* in_sizes, int n_in,
                              void* d_out, int out_size, void* d_ws, size_t ws_size,
                              hipStream_t stream) {
    const float* x   = (const float*)d_in[0];
    const float* wgt = (const float*)d_in[1];
    float* out = (float*)d_out;
    const int ntok = in_sizes[0] / DIM;   // 32768

    unsigned short* wf    = (unsigned short*)d_ws;                   // 1 MB fragment image
    unsigned char*  flags = (unsigned char*)d_ws + FLAGS_OFF;        // ntok bytes

    hipLaunchKernelGGL(wsplit_kernel, dim3(64), dim3(256), 0, stream, wgt, wf);
    hipLaunchKernelGGL(moe_gate_mfma_kernel, dim3(ntok / TPB), dim3(256), 0, stream,
                       x, wf, out, ntok, flags);
    hipLaunchKernelGGL(moe_gate_refine_kernel, dim3(ntok / 4), dim3(64), 0, stream,
                       x, wgt, out, ntok, flags);
}